// Round 1
// baseline (365.000 us; speedup 1.0000x reference)
//
#include <hip/hip_runtime.h>
#include <hip/hip_bf16.h>

#define T_TOK 4096
#define H_DIM 1024
#define E_NUM 8
#define I_DIM 1024
#define PAD_CAP 9216   // 72 * 128 >= 8192 + 8*127

typedef __attribute__((ext_vector_type(4))) float f32x4;
typedef __attribute__((ext_vector_type(8))) short bf16x8;

__device__ __forceinline__ unsigned short f2b(float f) {
  union { float f; unsigned int u; } v; v.f = f;
  unsigned int r = v.u + 0x7fffu + ((v.u >> 16) & 1u);  // RNE to bf16
  return (unsigned short)(r >> 16);
}

__device__ __forceinline__ void async_copy16(const void* g, void* l) {
  __builtin_amdgcn_global_load_lds(
      (const __attribute__((address_space(1))) void*)g,
      (__attribute__((address_space(3))) void*)l, 16, 0, 0);
}

// ---------------- routing ----------------
__global__ void k_router(const float* __restrict__ logits,
                         const float* __restrict__ scale,
                         int* __restrict__ counts,
                         int* __restrict__ tids,
                         float* __restrict__ cw) {
  int t = blockIdx.x * 256 + threadIdx.x;
  if (t >= T_TOK) return;
  float l[E_NUM];
#pragma unroll
  for (int i = 0; i < E_NUM; ++i) l[i] = logits[t * E_NUM + i];
  float m = l[0];
#pragma unroll
  for (int i = 1; i < E_NUM; ++i) m = fmaxf(m, l[i]);
  float p[E_NUM]; float s = 0.f;
#pragma unroll
  for (int i = 0; i < E_NUM; ++i) { p[i] = expf(l[i] - m); s += p[i]; }
  float inv = 1.f / s;
  int i0 = 0; float b0 = l[0];
#pragma unroll
  for (int i = 1; i < E_NUM; ++i) if (l[i] > b0) { b0 = l[i]; i0 = i; }
  int i1 = -1; float b1 = -1e30f;
#pragma unroll
  for (int i = 0; i < E_NUM; ++i) if (i != i0 && l[i] > b1) { b1 = l[i]; i1 = i; }
  float g0 = p[i0] * inv, g1 = p[i1] * inv;
  float r = g0 + g1;
  float c0 = g0 / r * scale[i0];
  float c1 = g1 / r * scale[i1];
  tids[t * 2] = i0; tids[t * 2 + 1] = i1;
  cw[t * 2] = c0;  cw[t * 2 + 1] = c1;
  atomicAdd(&counts[i0], 1);
  atomicAdd(&counts[i1], 1);
}

__global__ void k_scan(const int* __restrict__ counts, int* __restrict__ pad_off,
                       int* __restrict__ cursor) {
  if (threadIdx.x == 0 && blockIdx.x == 0) {
    int off = 0;
    for (int e = 0; e < E_NUM; ++e) {
      pad_off[e] = off; cursor[e] = off;
      off += (counts[e] + 127) & ~127;
    }
    pad_off[E_NUM] = off;
  }
}

__global__ void k_scatter(const int* __restrict__ tids, int* __restrict__ cursor,
                          int* __restrict__ perm) {
  int t = blockIdx.x * 256 + threadIdx.x;
  if (t >= T_TOK) return;
#pragma unroll
  for (int k = 0; k < 2; ++k) {
    int e = tids[t * 2 + k];
    int slot = atomicAdd(&cursor[e], 1);
    perm[slot] = t * 2 + k;
  }
}

// ---------------- x -> bf16 ----------------
__global__ void k_xconv(const float4* __restrict__ x, uint2* __restrict__ xbf) {
  int i = blockIdx.x * 256 + threadIdx.x;
  float4 v = x[i];
  uint2 o;
  o.x = (unsigned)f2b(v.x) | ((unsigned)f2b(v.y) << 16);
  o.y = (unsigned)f2b(v.z) | ((unsigned)f2b(v.w) << 16);
  xbf[i] = o;
}

// ---------------- GEMM1: h = gelu(x@w1^T) * (x@w3^T) ----------------
// block: 128 rows (padded expert rows) x 64 h-cols; B tile = 64 w1-rows ++ 64 w3-rows
__global__ __launch_bounds__(256, 2) void k_gemm1(
    const unsigned short* __restrict__ xbf, const float* __restrict__ w13,
    const int* __restrict__ perm, const int* __restrict__ pad_off,
    unsigned short* __restrict__ h_buf) {
  __shared__ __align__(16) unsigned short a_lds[128 * 64];
  __shared__ __align__(16) unsigned short b_lds[128 * 64];
  const int tid = threadIdx.x;
  const int wave = tid >> 6, lane = tid & 63;
  const int row0 = blockIdx.y * 128;
  if (row0 >= pad_off[E_NUM]) return;
  int e = 0;
#pragma unroll
  for (int i = 1; i < E_NUM; ++i) if (row0 >= pad_off[i]) e = i;
  const int iBase = blockIdx.x * 64;

  // A staging: lane covers row = j*32 + wave*8 + (lane>>3), 16B chunk (8 bf16).
  // XOR swizzle: LDS position chunk (lane&7) holds source chunk (lane&7)^(row&7).
  const int srcChunk = (lane & 7) ^ ((lane >> 3) & 7);
  const unsigned short* agbase[4];
#pragma unroll
  for (int j = 0; j < 4; ++j) {
    int r = j * 32 + wave * 8 + (lane >> 3);
    int p = perm[row0 + r];
    int tok = (p < 0) ? 0 : (p >> 1);
    agbase[j] = xbf + (size_t)tok * H_DIM + srcChunk * 8;
  }
  // B staging: f32 -> bf16 convert, 16B units, same XOR swizzle.
  const float* bgbase[4];
  int bdst[4];
#pragma unroll
  for (int u = 0; u < 4; ++u) {
    int flat = u * 256 + tid;
    int brow = flat >> 3;
    int chunk = flat & 7;
    int grow = (brow < 64) ? (iBase + brow) : (I_DIM + iBase + (brow - 64));
    bgbase[u] = w13 + ((size_t)e * 2 * I_DIM + grow) * H_DIM + chunk * 8;
    bdst[u] = brow * 64 + ((chunk ^ (brow & 7)) * 8);
  }

  f32x4 acc[2][8];
#pragma unroll
  for (int mi = 0; mi < 2; ++mi)
#pragma unroll
    for (int ni = 0; ni < 8; ++ni) acc[mi][ni] = (f32x4)(0.f);

  const int ml = lane & 15, quad = lane >> 4;

  for (int k0 = 0; k0 < H_DIM; k0 += 64) {
    __syncthreads();
#pragma unroll
    for (int j = 0; j < 4; ++j)
      async_copy16(agbase[j] + k0, a_lds + (j * 256 + wave * 64) * 8);
#pragma unroll
    for (int u = 0; u < 4; ++u) {
      const float4* src = (const float4*)(bgbase[u] + k0);
      float4 f0 = src[0], f1 = src[1];
      uint4 pk;
      pk.x = (unsigned)f2b(f0.x) | ((unsigned)f2b(f0.y) << 16);
      pk.y = (unsigned)f2b(f0.z) | ((unsigned)f2b(f0.w) << 16);
      pk.z = (unsigned)f2b(f1.x) | ((unsigned)f2b(f1.y) << 16);
      pk.w = (unsigned)f2b(f1.z) | ((unsigned)f2b(f1.w) << 16);
      *(uint4*)(b_lds + bdst[u]) = pk;
    }
    __syncthreads();
#pragma unroll
    for (int ks = 0; ks < 2; ++ks) {
      const int ch = ((ks * 4 + quad) ^ (ml & 7)) * 8;
      bf16x8 af[2];
#pragma unroll
      for (int mi = 0; mi < 2; ++mi)
        af[mi] = *(const bf16x8*)(a_lds + (wave * 32 + mi * 16 + ml) * 64 + ch);
#pragma unroll
      for (int ni = 0; ni < 8; ++ni) {
        bf16x8 bfr = *(const bf16x8*)(b_lds + (ni * 16 + ml) * 64 + ch);
#pragma unroll
        for (int mi = 0; mi < 2; ++mi)
          acc[mi][ni] = __builtin_amdgcn_mfma_f32_16x16x32_bf16(af[mi], bfr, acc[mi][ni], 0, 0, 0);
      }
    }
  }
  // epilogue: h = gelu_exact(g) * u ; cols 0..63 are g (ni), 64..127 are u (ni+4)
#pragma unroll
  for (int mi = 0; mi < 2; ++mi) {
#pragma unroll
    for (int ni = 0; ni < 4; ++ni) {
      f32x4 g = acc[mi][ni];
      f32x4 uu = acc[mi][ni + 4];
#pragma unroll
      for (int r = 0; r < 4; ++r) {
        int lrow = wave * 32 + mi * 16 + quad * 4 + r;
        float gg = g[r];
        float hv = 0.5f * gg * (1.f + erff(gg * 0.7071067811865475f)) * uu[r];
        h_buf[(size_t)(row0 + lrow) * I_DIM + iBase + ni * 16 + ml] = f2b(hv);
      }
    }
  }
}

// ---------------- GEMM2: y = h @ w2^T, out[t] += cw * y ----------------
__global__ __launch_bounds__(256, 2) void k_gemm2(
    const unsigned short* __restrict__ h_buf, const float* __restrict__ w2,
    const int* __restrict__ perm, const int* __restrict__ pad_off,
    const float* __restrict__ cw, float* __restrict__ out) {
  __shared__ __align__(16) unsigned short a_lds[128 * 64];
  __shared__ __align__(16) unsigned short b_lds[128 * 64];
  __shared__ int s_tok[128];
  __shared__ float s_cw[128];
  const int tid = threadIdx.x;
  const int wave = tid >> 6, lane = tid & 63;
  const int row0 = blockIdx.y * 128;
  if (row0 >= pad_off[E_NUM]) return;
  int e = 0;
#pragma unroll
  for (int i = 1; i < E_NUM; ++i) if (row0 >= pad_off[i]) e = i;
  const int cBase = blockIdx.x * 128;
  if (tid < 128) {
    int p = perm[row0 + tid];
    s_tok[tid] = (p < 0) ? -1 : (p >> 1);
    s_cw[tid] = (p < 0) ? 0.f : cw[p];
  }
  const int srcChunk = (lane & 7) ^ ((lane >> 3) & 7);
  const unsigned short* agbase[4];
#pragma unroll
  for (int j = 0; j < 4; ++j) {
    int r = j * 32 + wave * 8 + (lane >> 3);
    agbase[j] = h_buf + (size_t)(row0 + r) * I_DIM + srcChunk * 8;
  }
  const float* bgbase[4];
  int bdst[4];
#pragma unroll
  for (int u = 0; u < 4; ++u) {
    int flat = u * 256 + tid;
    int brow = flat >> 3;
    int chunk = flat & 7;
    bgbase[u] = w2 + ((size_t)e * H_DIM + cBase + brow) * I_DIM + chunk * 8;
    bdst[u] = brow * 64 + ((chunk ^ (brow & 7)) * 8);
  }
  f32x4 acc[4][4];
#pragma unroll
  for (int mi = 0; mi < 4; ++mi)
#pragma unroll
    for (int ni = 0; ni < 4; ++ni) acc[mi][ni] = (f32x4)(0.f);
  const int wm = wave >> 1, wn = wave & 1;
  const int ml = lane & 15, quad = lane >> 4;

  for (int k0 = 0; k0 < I_DIM; k0 += 64) {
    __syncthreads();
#pragma unroll
    for (int j = 0; j < 4; ++j)
      async_copy16(agbase[j] + k0, a_lds + (j * 256 + wave * 64) * 8);
#pragma unroll
    for (int u = 0; u < 4; ++u) {
      const float4* src = (const float4*)(bgbase[u] + k0);
      float4 f0 = src[0], f1 = src[1];
      uint4 pk;
      pk.x = (unsigned)f2b(f0.x) | ((unsigned)f2b(f0.y) << 16);
      pk.y = (unsigned)f2b(f0.z) | ((unsigned)f2b(f0.w) << 16);
      pk.z = (unsigned)f2b(f1.x) | ((unsigned)f2b(f1.y) << 16);
      pk.w = (unsigned)f2b(f1.z) | ((unsigned)f2b(f1.w) << 16);
      *(uint4*)(b_lds + bdst[u]) = pk;
    }
    __syncthreads();
#pragma unroll
    for (int ks = 0; ks < 2; ++ks) {
      const int ch = ((ks * 4 + quad) ^ (ml & 7)) * 8;
      bf16x8 af[4], bfr[4];
#pragma unroll
      for (int mi = 0; mi < 4; ++mi)
        af[mi] = *(const bf16x8*)(a_lds + (wm * 64 + mi * 16 + ml) * 64 + ch);
#pragma unroll
      for (int ni = 0; ni < 4; ++ni)
        bfr[ni] = *(const bf16x8*)(b_lds + (wn * 64 + ni * 16 + ml) * 64 + ch);
#pragma unroll
      for (int mi = 0; mi < 4; ++mi)
#pragma unroll
        for (int ni = 0; ni < 4; ++ni)
          acc[mi][ni] = __builtin_amdgcn_mfma_f32_16x16x32_bf16(af[mi], bfr[ni], acc[mi][ni], 0, 0, 0);
    }
  }
#pragma unroll
  for (int mi = 0; mi < 4; ++mi) {
#pragma unroll
    for (int ni = 0; ni < 4; ++ni) {
#pragma unroll
      for (int r = 0; r < 4; ++r) {
        int lrow = wm * 64 + mi * 16 + quad * 4 + r;
        int tok = s_tok[lrow];
        if (tok >= 0)
          atomicAdd(&out[(size_t)tok * H_DIM + cBase + wn * 64 + ni * 16 + ml],
                    s_cw[lrow] * acc[mi][ni][r]);
      }
    }
  }
}

extern "C" void kernel_launch(void* const* d_in, const int* in_sizes, int n_in,
                              void* d_out, int out_size, void* d_ws, size_t ws_size,
                              hipStream_t stream) {
  const float* x      = (const float*)d_in[0];
  const float* logits = (const float*)d_in[1];
  const float* scale  = (const float*)d_in[2];
  const float* w13    = (const float*)d_in[3];
  const float* w2     = (const float*)d_in[4];
  float* out = (float*)d_out;

  char* ws = (char*)d_ws;
  int*   counts  = (int*)(ws + 0);
  int*   cursor  = (int*)(ws + 64);
  int*   pad_off = (int*)(ws + 128);
  int*   tids    = (int*)(ws + 4096);       // T*2 ints
  float* cw      = (float*)(ws + 65536);    // T*2 floats
  int*   perm    = (int*)(ws + 131072);     // PAD_CAP ints
  unsigned short* xbf   = (unsigned short*)(ws + (1u << 20));   // T*H bf16 (8 MB)
  unsigned short* h_buf = (unsigned short*)(ws + (16u << 20));  // PAD_CAP*I bf16 (~19 MB)

  hipMemsetAsync(ws, 0, 256, stream);
  hipMemsetAsync(ws + 131072, 0xFF, PAD_CAP * 4, stream);
  hipMemsetAsync(d_out, 0, (size_t)T_TOK * H_DIM * sizeof(float), stream);

  k_router<<<T_TOK / 256, 256, 0, stream>>>(logits, scale, counts, tids, cw);
  k_scan<<<1, 1, 0, stream>>>(counts, pad_off, cursor);
  k_scatter<<<T_TOK / 256, 256, 0, stream>>>(tids, cursor, perm);
  k_xconv<<<(T_TOK * H_DIM) / 1024, 256, 0, stream>>>((const float4*)x, (uint2*)xbf);
  k_gemm1<<<dim3(I_DIM / 64, PAD_CAP / 128), 256, 0, stream>>>(xbf, w13, perm, pad_off, h_buf);
  k_gemm2<<<dim3(H_DIM / 128, PAD_CAP / 128), 256, 0, stream>>>(h_buf, w2, perm, pad_off, cw, out);
}

// Round 2
// 325.877 us; speedup vs baseline: 1.1201x; 1.1201x over previous
//
#include <hip/hip_runtime.h>
#include <hip/hip_bf16.h>

#define T_TOK 4096
#define H_DIM 1024
#define E_NUM 8
#define I_DIM 1024
#define PAD_CAP 9216   // 72 * 128 >= 8192 + 8*127

typedef __attribute__((ext_vector_type(4))) float f32x4;
typedef __attribute__((ext_vector_type(8))) short bf16x8;

__device__ __forceinline__ unsigned short f2b(float f) {
  union { float f; unsigned int u; } v; v.f = f;
  unsigned int r = v.u + 0x7fffu + ((v.u >> 16) & 1u);  // RNE to bf16
  return (unsigned short)(r >> 16);
}

__device__ __forceinline__ void async_copy16(const void* g, void* l) {
  __builtin_amdgcn_global_load_lds(
      (const __attribute__((address_space(1))) void*)g,
      (__attribute__((address_space(3))) void*)l, 16, 0, 0);
}

// ---------------- routing ----------------
__global__ void k_router(const float* __restrict__ logits,
                         const float* __restrict__ scale,
                         int* __restrict__ counts,
                         int* __restrict__ tids,
                         float* __restrict__ cw) {
  int t = blockIdx.x * 256 + threadIdx.x;
  if (t >= T_TOK) return;
  float l[E_NUM];
#pragma unroll
  for (int i = 0; i < E_NUM; ++i) l[i] = logits[t * E_NUM + i];
  float m = l[0];
#pragma unroll
  for (int i = 1; i < E_NUM; ++i) m = fmaxf(m, l[i]);
  float p[E_NUM]; float s = 0.f;
#pragma unroll
  for (int i = 0; i < E_NUM; ++i) { p[i] = expf(l[i] - m); s += p[i]; }
  float inv = 1.f / s;
  int i0 = 0; float b0 = l[0];
#pragma unroll
  for (int i = 1; i < E_NUM; ++i) if (l[i] > b0) { b0 = l[i]; i0 = i; }
  int i1 = -1; float b1 = -1e30f;
#pragma unroll
  for (int i = 0; i < E_NUM; ++i) if (i != i0 && l[i] > b1) { b1 = l[i]; i1 = i; }
  float g0 = p[i0] * inv, g1 = p[i1] * inv;
  float r = g0 + g1;
  float c0 = g0 / r * scale[i0];
  float c1 = g1 / r * scale[i1];
  tids[t * 2] = i0; tids[t * 2 + 1] = i1;
  cw[t * 2] = c0;  cw[t * 2 + 1] = c1;
  atomicAdd(&counts[i0], 1);
  atomicAdd(&counts[i1], 1);
}

__global__ void k_scan(const int* __restrict__ counts, int* __restrict__ pad_off,
                       int* __restrict__ cursor) {
  if (threadIdx.x == 0 && blockIdx.x == 0) {
    int off = 0;
    for (int e = 0; e < E_NUM; ++e) {
      pad_off[e] = off; cursor[e] = off;
      off += (counts[e] + 127) & ~127;
    }
    pad_off[E_NUM] = off;
  }
}

__global__ void k_scatter(const int* __restrict__ tids, int* __restrict__ cursor,
                          int* __restrict__ perm) {
  int t = blockIdx.x * 256 + threadIdx.x;
  if (t >= T_TOK) return;
#pragma unroll
  for (int k = 0; k < 2; ++k) {
    int e = tids[t * 2 + k];
    int slot = atomicAdd(&cursor[e], 1);
    perm[slot] = t * 2 + k;
  }
}

// ---------------- generic f32 -> bf16, 8 floats/thread ----------------
__global__ void k_conv(const float* __restrict__ src, unsigned short* __restrict__ dst) {
  size_t i = ((size_t)blockIdx.x * 256 + threadIdx.x) * 8;
  float4 f0 = *(const float4*)(src + i);
  float4 f1 = *(const float4*)(src + i + 4);
  uint4 pk;
  pk.x = (unsigned)f2b(f0.x) | ((unsigned)f2b(f0.y) << 16);
  pk.y = (unsigned)f2b(f0.z) | ((unsigned)f2b(f0.w) << 16);
  pk.z = (unsigned)f2b(f1.x) | ((unsigned)f2b(f1.y) << 16);
  pk.w = (unsigned)f2b(f1.z) | ((unsigned)f2b(f1.w) << 16);
  *(uint4*)(dst + i) = pk;
}

// ---------------- GEMM1: h = gelu(x@w1^T) * (x@w3^T) ----------------
// 128 padded rows x 64 unique i-cols. B tile = 128 rows interleaved:
// brow seg=brow>>5: half=seg&1 (0:w1,1:w3), col=iBase+(seg>>1)*32+(brow&31).
// Wave (wm,wn) 2x2; wave's ni 0,1 = g cols, ni 2,3 = matching u cols.
template <bool PRE>
__global__ __launch_bounds__(256, 2) void k_gemm1(
    const unsigned short* __restrict__ xbf,
    const unsigned short* __restrict__ w13b,
    const float* __restrict__ w13f,
    const int* __restrict__ perm, const int* __restrict__ pad_off,
    unsigned short* __restrict__ h_buf) {
  __shared__ __align__(16) unsigned short a_lds[128 * 64];
  __shared__ __align__(16) unsigned short b_lds[128 * 64];
  const int tid = threadIdx.x;
  const int wave = tid >> 6, lane = tid & 63;
  const int row0 = blockIdx.y * 128;
  if (row0 >= pad_off[E_NUM]) return;
  int e = 0;
#pragma unroll
  for (int i = 1; i < E_NUM; ++i) if (row0 >= pad_off[i]) e = i;
  const int iBase = blockIdx.x * 64;

  // XOR swizzle: LDS chunk position (lane&7) of a row holds source chunk pos^(row&7)
  const int srcChunk = (lane & 7) ^ ((lane >> 3) & 7);

  const unsigned short* agbase[4];
#pragma unroll
  for (int j = 0; j < 4; ++j) {
    int r = j * 32 + wave * 8 + (lane >> 3);
    int p = perm[row0 + r];
    int tok = (p < 0) ? 0 : (p >> 1);
    agbase[j] = xbf + (size_t)tok * H_DIM + srcChunk * 8;
  }

  const unsigned short* bgbase[4];
  const float* bgbasef[4];
  int bdstf[4];
  if constexpr (PRE) {
#pragma unroll
    for (int j = 0; j < 4; ++j) {
      int brow = j * 32 + wave * 8 + (lane >> 3);
      int seg = brow >> 5, half = seg & 1;
      int col = iBase + (seg >> 1) * 32 + (brow & 31);
      bgbase[j] = w13b + ((size_t)e * 2 * I_DIM + half * I_DIM + col) * H_DIM + srcChunk * 8;
    }
  } else {
#pragma unroll
    for (int u = 0; u < 4; ++u) {
      int flat = u * 256 + tid;
      int brow = flat >> 3, chunk = flat & 7;
      int seg = brow >> 5, half = seg & 1;
      int col = iBase + (seg >> 1) * 32 + (brow & 31);
      bgbasef[u] = w13f + ((size_t)e * 2 * I_DIM + half * I_DIM + col) * H_DIM + chunk * 8;
      bdstf[u] = brow * 64 + ((chunk ^ (brow & 7)) * 8);
    }
  }

  f32x4 acc[4][4];
#pragma unroll
  for (int mi = 0; mi < 4; ++mi)
#pragma unroll
    for (int ni = 0; ni < 4; ++ni) acc[mi][ni] = (f32x4)(0.f);

  const int wm = wave >> 1, wn = wave & 1;
  const int ml = lane & 15, quad = lane >> 4;

  for (int k0 = 0; k0 < H_DIM; k0 += 64) {
    __syncthreads();
#pragma unroll
    for (int j = 0; j < 4; ++j)
      async_copy16(agbase[j] + k0, a_lds + (j * 256 + wave * 64) * 8);
    if constexpr (PRE) {
#pragma unroll
      for (int j = 0; j < 4; ++j)
        async_copy16(bgbase[j] + k0, b_lds + (j * 256 + wave * 64) * 8);
    } else {
#pragma unroll
      for (int u = 0; u < 4; ++u) {
        const float4* src = (const float4*)(bgbasef[u] + k0);
        float4 f0 = src[0], f1 = src[1];
        uint4 pk;
        pk.x = (unsigned)f2b(f0.x) | ((unsigned)f2b(f0.y) << 16);
        pk.y = (unsigned)f2b(f0.z) | ((unsigned)f2b(f0.w) << 16);
        pk.z = (unsigned)f2b(f1.x) | ((unsigned)f2b(f1.y) << 16);
        pk.w = (unsigned)f2b(f1.z) | ((unsigned)f2b(f1.w) << 16);
        *(uint4*)(b_lds + bdstf[u]) = pk;
      }
    }
    __syncthreads();
#pragma unroll
    for (int ks = 0; ks < 2; ++ks) {
      const int ch = ((ks * 4 + quad) ^ (ml & 7)) * 8;
      bf16x8 af[4], bfr[4];
#pragma unroll
      for (int mi = 0; mi < 4; ++mi)
        af[mi] = *(const bf16x8*)(a_lds + (wm * 64 + mi * 16 + ml) * 64 + ch);
#pragma unroll
      for (int ni = 0; ni < 4; ++ni)
        bfr[ni] = *(const bf16x8*)(b_lds + (wn * 64 + ni * 16 + ml) * 64 + ch);
#pragma unroll
      for (int mi = 0; mi < 4; ++mi)
#pragma unroll
        for (int ni = 0; ni < 4; ++ni)
          acc[mi][ni] = __builtin_amdgcn_mfma_f32_16x16x32_bf16(af[mi], bfr[ni], acc[mi][ni], 0, 0, 0);
    }
  }
  // epilogue: ni in {0,1} = g, ni+2 = matching u; col = iBase + wn*32 + ni*16 + ml
#pragma unroll
  for (int mi = 0; mi < 4; ++mi) {
#pragma unroll
    for (int nc = 0; nc < 2; ++nc) {
      f32x4 g = acc[mi][nc];
      f32x4 uu = acc[mi][nc + 2];
#pragma unroll
      for (int r = 0; r < 4; ++r) {
        int row = row0 + wm * 64 + mi * 16 + quad * 4 + r;
        int col = iBase + wn * 32 + nc * 16 + ml;
        float gg = g[r];
        float hv = 0.5f * gg * (1.f + erff(gg * 0.7071067811865475f)) * uu[r];
        h_buf[(size_t)row * I_DIM + col] = f2b(hv);
      }
    }
  }
}

// ---------------- GEMM2: y = h @ w2^T, out[t] += cw * y ----------------
template <bool PRE>
__global__ __launch_bounds__(256, 2) void k_gemm2(
    const unsigned short* __restrict__ h_buf,
    const unsigned short* __restrict__ w2b,
    const float* __restrict__ w2f,
    const int* __restrict__ perm, const int* __restrict__ pad_off,
    const float* __restrict__ cw, float* __restrict__ out) {
  __shared__ __align__(16) unsigned short a_lds[128 * 64];
  __shared__ __align__(16) unsigned short b_lds[128 * 64];
  __shared__ int s_tok[128];
  __shared__ float s_cw[128];
  const int tid = threadIdx.x;
  const int wave = tid >> 6, lane = tid & 63;
  const int row0 = blockIdx.y * 128;
  if (row0 >= pad_off[E_NUM]) return;
  int e = 0;
#pragma unroll
  for (int i = 1; i < E_NUM; ++i) if (row0 >= pad_off[i]) e = i;
  const int cBase = blockIdx.x * 128;
  if (tid < 128) {
    int p = perm[row0 + tid];
    s_tok[tid] = (p < 0) ? -1 : (p >> 1);
    s_cw[tid] = (p < 0) ? 0.f : cw[p];
  }
  const int srcChunk = (lane & 7) ^ ((lane >> 3) & 7);
  const unsigned short* agbase[4];
#pragma unroll
  for (int j = 0; j < 4; ++j) {
    int r = j * 32 + wave * 8 + (lane >> 3);
    agbase[j] = h_buf + (size_t)(row0 + r) * I_DIM + srcChunk * 8;
  }
  const unsigned short* bgbase[4];
  const float* bgbasef[4];
  int bdstf[4];
  if constexpr (PRE) {
#pragma unroll
    for (int j = 0; j < 4; ++j) {
      int brow = j * 32 + wave * 8 + (lane >> 3);
      bgbase[j] = w2b + ((size_t)e * H_DIM + cBase + brow) * I_DIM + srcChunk * 8;
    }
  } else {
#pragma unroll
    for (int u = 0; u < 4; ++u) {
      int flat = u * 256 + tid;
      int brow = flat >> 3, chunk = flat & 7;
      bgbasef[u] = w2f + ((size_t)e * H_DIM + cBase + brow) * I_DIM + chunk * 8;
      bdstf[u] = brow * 64 + ((chunk ^ (brow & 7)) * 8);
    }
  }
  f32x4 acc[4][4];
#pragma unroll
  for (int mi = 0; mi < 4; ++mi)
#pragma unroll
    for (int ni = 0; ni < 4; ++ni) acc[mi][ni] = (f32x4)(0.f);
  const int wm = wave >> 1, wn = wave & 1;
  const int ml = lane & 15, quad = lane >> 4;

  for (int k0 = 0; k0 < I_DIM; k0 += 64) {
    __syncthreads();
#pragma unroll
    for (int j = 0; j < 4; ++j)
      async_copy16(agbase[j] + k0, a_lds + (j * 256 + wave * 64) * 8);
    if constexpr (PRE) {
#pragma unroll
      for (int j = 0; j < 4; ++j)
        async_copy16(bgbase[j] + k0, b_lds + (j * 256 + wave * 64) * 8);
    } else {
#pragma unroll
      for (int u = 0; u < 4; ++u) {
        const float4* src = (const float4*)(bgbasef[u] + k0);
        float4 f0 = src[0], f1 = src[1];
        uint4 pk;
        pk.x = (unsigned)f2b(f0.x) | ((unsigned)f2b(f0.y) << 16);
        pk.y = (unsigned)f2b(f0.z) | ((unsigned)f2b(f0.w) << 16);
        pk.z = (unsigned)f2b(f1.x) | ((unsigned)f2b(f1.y) << 16);
        pk.w = (unsigned)f2b(f1.z) | ((unsigned)f2b(f1.w) << 16);
        *(uint4*)(b_lds + bdstf[u]) = pk;
      }
    }
    __syncthreads();
#pragma unroll
    for (int ks = 0; ks < 2; ++ks) {
      const int ch = ((ks * 4 + quad) ^ (ml & 7)) * 8;
      bf16x8 af[4], bfr[4];
#pragma unroll
      for (int mi = 0; mi < 4; ++mi)
        af[mi] = *(const bf16x8*)(a_lds + (wm * 64 + mi * 16 + ml) * 64 + ch);
#pragma unroll
      for (int ni = 0; ni < 4; ++ni)
        bfr[ni] = *(const bf16x8*)(b_lds + (wn * 64 + ni * 16 + ml) * 64 + ch);
#pragma unroll
      for (int mi = 0; mi < 4; ++mi)
#pragma unroll
        for (int ni = 0; ni < 4; ++ni)
          acc[mi][ni] = __builtin_amdgcn_mfma_f32_16x16x32_bf16(af[mi], bfr[ni], acc[mi][ni], 0, 0, 0);
    }
  }
#pragma unroll
  for (int mi = 0; mi < 4; ++mi) {
#pragma unroll
    for (int ni = 0; ni < 4; ++ni) {
#pragma unroll
      for (int r = 0; r < 4; ++r) {
        int lrow = wm * 64 + mi * 16 + quad * 4 + r;
        int tok = s_tok[lrow];
        if (tok >= 0)
          atomicAdd(&out[(size_t)tok * H_DIM + cBase + wn * 64 + ni * 16 + ml],
                    s_cw[lrow] * acc[mi][ni][r]);
      }
    }
  }
}

extern "C" void kernel_launch(void* const* d_in, const int* in_sizes, int n_in,
                              void* d_out, int out_size, void* d_ws, size_t ws_size,
                              hipStream_t stream) {
  const float* x      = (const float*)d_in[0];
  const float* logits = (const float*)d_in[1];
  const float* scale  = (const float*)d_in[2];
  const float* w13    = (const float*)d_in[3];
  const float* w2     = (const float*)d_in[4];
  float* out = (float*)d_out;

  char* ws = (char*)d_ws;
  int*   counts  = (int*)(ws + 0);
  int*   cursor  = (int*)(ws + 64);
  int*   pad_off = (int*)(ws + 128);
  int*   tids    = (int*)(ws + 4096);             // T*2 ints (32 KB)
  float* cw      = (float*)(ws + 65536);          // T*2 floats (32 KB)
  int*   perm    = (int*)(ws + 131072);           // PAD_CAP ints (36 KB)
  unsigned short* xb    = (unsigned short*)(ws + 0x40000);    // 256 KB: x bf16 (8 MB)
  unsigned short* h_buf = (unsigned short*)(ws + 0x900000);   // 9 MB: h bf16 (~18.9 MB)
  unsigned short* w13b  = (unsigned short*)(ws + 0x1C00000);  // 28 MB: w13 bf16 (32 MB)
  unsigned short* w2b   = (unsigned short*)(ws + 0x3C00000);  // 60 MB: w2 bf16 (16 MB)
  const bool pre1 = ws_size >= (size_t)0x3C00000;  // w13b fits
  const bool pre2 = ws_size >= (size_t)0x4C00000;  // w2b fits too

  hipMemsetAsync(ws, 0, 256, stream);
  hipMemsetAsync(ws + 131072, 0xFF, PAD_CAP * 4, stream);
  hipMemsetAsync(d_out, 0, (size_t)T_TOK * H_DIM * sizeof(float), stream);

  k_router<<<T_TOK / 256, 256, 0, stream>>>(logits, scale, counts, tids, cw);
  k_scan<<<1, 1, 0, stream>>>(counts, pad_off, cursor);
  k_scatter<<<T_TOK / 256, 256, 0, stream>>>(tids, cursor, perm);
  k_conv<<<(T_TOK * H_DIM) / 2048, 256, 0, stream>>>(x, xb);
  if (pre1) k_conv<<<(E_NUM * 2 * I_DIM * H_DIM) / 2048, 256, 0, stream>>>(w13, w13b);
  if (pre2) k_conv<<<(E_NUM * H_DIM * I_DIM) / 2048, 256, 0, stream>>>(w2, w2b);

  if (pre1)
    k_gemm1<true><<<dim3(I_DIM / 64, PAD_CAP / 128), 256, 0, stream>>>(xb, w13b, w13, perm, pad_off, h_buf);
  else
    k_gemm1<false><<<dim3(I_DIM / 64, PAD_CAP / 128), 256, 0, stream>>>(xb, w13b, w13, perm, pad_off, h_buf);
  if (pre2)
    k_gemm2<true><<<dim3(H_DIM / 128, PAD_CAP / 128), 256, 0, stream>>>(h_buf, w2b, w2, perm, pad_off, cw, out);
  else
    k_gemm2<false><<<dim3(H_DIM / 128, PAD_CAP / 128), 256, 0, stream>>>(h_buf, w2b, w2, perm, pad_off, cw, out);
}

// Round 3
// 300.584 us; speedup vs baseline: 1.2143x; 1.0841x over previous
//
#include <hip/hip_runtime.h>
#include <hip/hip_bf16.h>

#define T_TOK 4096
#define H_DIM 1024
#define E_NUM 8
#define I_DIM 1024
#define PAD_CAP 9216   // 72 * 128 >= 8192 + 8*127

typedef __attribute__((ext_vector_type(4))) float f32x4;
typedef __attribute__((ext_vector_type(8))) short bf16x8;

__device__ __forceinline__ unsigned short f2b(float f) {
  union { float f; unsigned int u; } v; v.f = f;
  unsigned int r = v.u + 0x7fffu + ((v.u >> 16) & 1u);  // RNE to bf16
  return (unsigned short)(r >> 16);
}

__device__ __forceinline__ void async_copy16(const void* g, void* l) {
  __builtin_amdgcn_global_load_lds(
      (const __attribute__((address_space(1))) void*)g,
      (__attribute__((address_space(3))) void*)l, 16, 0, 0);
}

// ---------------- routing: one block does top2+softmax+histogram+scan+scatter+pad ----
__global__ __launch_bounds__(1024) void k_route(
    const float* __restrict__ logits, const float* __restrict__ scale,
    int* __restrict__ pad_off, int* __restrict__ perm,
    int* __restrict__ inv, float* __restrict__ cw) {
  __shared__ int s_cnt[E_NUM], s_off[E_NUM], s_cur[E_NUM];
  const int tid = threadIdx.x;
  if (tid < E_NUM) s_cnt[tid] = 0;
  __syncthreads();
  int e0[4], e1[4];
#pragma unroll
  for (int it = 0; it < 4; ++it) {
    int t = it * 1024 + tid;
    float l[E_NUM];
    *(float4*)(l)     = *(const float4*)(logits + (size_t)t * E_NUM);
    *(float4*)(l + 4) = *(const float4*)(logits + (size_t)t * E_NUM + 4);
    float m = l[0];
#pragma unroll
    for (int i = 1; i < E_NUM; ++i) m = fmaxf(m, l[i]);
    float p[E_NUM]; float s = 0.f;
#pragma unroll
    for (int i = 0; i < E_NUM; ++i) { p[i] = expf(l[i] - m); s += p[i]; }
    int i0 = 0; float b0 = l[0];
#pragma unroll
    for (int i = 1; i < E_NUM; ++i) if (l[i] > b0) { b0 = l[i]; i0 = i; }
    int i1 = -1; float b1 = -1e30f;
#pragma unroll
    for (int i = 0; i < E_NUM; ++i) if (i != i0 && l[i] > b1) { b1 = l[i]; i1 = i; }
    float g0 = p[i0] / s, g1 = p[i1] / s;
    float r = g0 + g1;
    cw[t * 2]     = g0 / r * scale[i0];
    cw[t * 2 + 1] = g1 / r * scale[i1];
    e0[it] = i0; e1[it] = i1;
    atomicAdd(&s_cnt[i0], 1);
    atomicAdd(&s_cnt[i1], 1);
  }
  __syncthreads();
  if (tid == 0) {
    int off = 0;
    for (int e = 0; e < E_NUM; ++e) {
      s_off[e] = off; s_cur[e] = off; pad_off[e] = off;
      off += (s_cnt[e] + 127) & ~127;
    }
    pad_off[E_NUM] = off;
  }
  __syncthreads();
#pragma unroll
  for (int it = 0; it < 4; ++it) {
    int t = it * 1024 + tid;
    int sl0 = atomicAdd(&s_cur[e0[it]], 1);
    perm[sl0] = t * 2;     inv[t * 2] = sl0;
    int sl1 = atomicAdd(&s_cur[e1[it]], 1);
    perm[sl1] = t * 2 + 1; inv[t * 2 + 1] = sl1;
  }
  __syncthreads();  // s_cur[e] == s_off[e] + s_cnt[e] now
  for (int e = 0; e < E_NUM; ++e) {
    int start = s_off[e] + s_cnt[e];
    int end   = s_off[e] + ((s_cnt[e] + 127) & ~127);
    for (int i = start + tid; i < end; i += 1024) perm[i] = -1;
  }
}

// ---------------- fused f32 -> bf16 for x, w13, w2 (2048 elems/block) ----------------
__global__ void k_conv3(const float* __restrict__ x, const float* __restrict__ w13,
                        const float* __restrict__ w2,
                        unsigned short* __restrict__ xb,
                        unsigned short* __restrict__ w13b,
                        unsigned short* __restrict__ w2b) {
  int b = blockIdx.x;
  const float* src; unsigned short* dst; size_t base;
  if (b < 2048)       { src = x;   dst = xb;   base = (size_t)b * 2048; }
  else if (b < 10240) { src = w13; dst = w13b; base = (size_t)(b - 2048) * 2048; }
  else                { src = w2;  dst = w2b;  base = (size_t)(b - 10240) * 2048; }
  size_t i = base + (size_t)threadIdx.x * 8;
  float4 f0 = *(const float4*)(src + i);
  float4 f1 = *(const float4*)(src + i + 4);
  uint4 pk;
  pk.x = (unsigned)f2b(f0.x) | ((unsigned)f2b(f0.y) << 16);
  pk.y = (unsigned)f2b(f0.z) | ((unsigned)f2b(f0.w) << 16);
  pk.z = (unsigned)f2b(f1.x) | ((unsigned)f2b(f1.y) << 16);
  pk.w = (unsigned)f2b(f1.z) | ((unsigned)f2b(f1.w) << 16);
  *(uint4*)(dst + i) = pk;
}

// XCD swizzle: all 16 col-blocks of a row-block get ids with the same (id % 8)
// -> same XCD -> A-tile stays in that XCD's L2.
__device__ __forceinline__ void swz_decode(int flat, int& rb, int& cb) {
  int q = flat >> 3;
  rb = (flat & 7) | ((q >> 4) << 3);   // 0..71
  cb = q & 15;                          // 0..15
}

// ---------------- GEMM1: h = gelu(x@w1^T) * (x@w3^T) ----------------
// 128 padded rows x 64 unique i-cols (128 MFMA cols: 64 w1-rows ++ 64 w3-rows
// interleaved in 32-row segments). Wave (wm,wn) 2x2; ni 0,1 = g, ni 2,3 = u.
__global__ __launch_bounds__(256, 4) void k_gemm1(
    const unsigned short* __restrict__ xbf,
    const unsigned short* __restrict__ w13b,
    const int* __restrict__ perm, const int* __restrict__ pad_off,
    unsigned short* __restrict__ h_buf) {
  __shared__ __align__(16) unsigned short a_lds[128 * 64];
  __shared__ __align__(16) unsigned short b_lds[128 * 64];
  const int tid = threadIdx.x;
  const int wave = tid >> 6, lane = tid & 63;
  int rb, cb; swz_decode(blockIdx.x, rb, cb);
  const int row0 = rb * 128;
  if (row0 >= pad_off[E_NUM]) return;
  int e = 0;
#pragma unroll
  for (int i = 1; i < E_NUM; ++i) if (row0 >= pad_off[i]) e = i;
  const int iBase = cb * 64;

  const int srcChunk = (lane & 7) ^ ((lane >> 3) & 7);

  const unsigned short* agbase[4];
#pragma unroll
  for (int j = 0; j < 4; ++j) {
    int r = j * 32 + wave * 8 + (lane >> 3);
    int p = perm[row0 + r];
    int tok = (p < 0) ? 0 : (p >> 1);
    agbase[j] = xbf + (size_t)tok * H_DIM + srcChunk * 8;
  }
  const unsigned short* bgbase[4];
#pragma unroll
  for (int j = 0; j < 4; ++j) {
    int brow = j * 32 + wave * 8 + (lane >> 3);
    int seg = brow >> 5, half = seg & 1;
    int col = iBase + (seg >> 1) * 32 + (brow & 31);
    bgbase[j] = w13b + ((size_t)e * 2 * I_DIM + half * I_DIM + col) * H_DIM + srcChunk * 8;
  }

  f32x4 acc[4][4];
#pragma unroll
  for (int mi = 0; mi < 4; ++mi)
#pragma unroll
    for (int ni = 0; ni < 4; ++ni) acc[mi][ni] = (f32x4)(0.f);

  const int wm = wave >> 1, wn = wave & 1;
  const int ml = lane & 15, quad = lane >> 4;

  for (int k0 = 0; k0 < H_DIM; k0 += 64) {
    __syncthreads();
#pragma unroll
    for (int j = 0; j < 4; ++j)
      async_copy16(agbase[j] + k0, a_lds + (j * 256 + wave * 64) * 8);
#pragma unroll
    for (int j = 0; j < 4; ++j)
      async_copy16(bgbase[j] + k0, b_lds + (j * 256 + wave * 64) * 8);
    __syncthreads();
#pragma unroll
    for (int ks = 0; ks < 2; ++ks) {
      const int ch = ((ks * 4 + quad) ^ (ml & 7)) * 8;
      bf16x8 af[4], bfr[4];
#pragma unroll
      for (int mi = 0; mi < 4; ++mi)
        af[mi] = *(const bf16x8*)(a_lds + (wm * 64 + mi * 16 + ml) * 64 + ch);
#pragma unroll
      for (int ni = 0; ni < 4; ++ni)
        bfr[ni] = *(const bf16x8*)(b_lds + (wn * 64 + ni * 16 + ml) * 64 + ch);
#pragma unroll
      for (int mi = 0; mi < 4; ++mi)
#pragma unroll
        for (int ni = 0; ni < 4; ++ni)
          acc[mi][ni] = __builtin_amdgcn_mfma_f32_16x16x32_bf16(af[mi], bfr[ni], acc[mi][ni], 0, 0, 0);
    }
  }
#pragma unroll
  for (int mi = 0; mi < 4; ++mi) {
#pragma unroll
    for (int nc = 0; nc < 2; ++nc) {
      f32x4 g = acc[mi][nc];
      f32x4 uu = acc[mi][nc + 2];
#pragma unroll
      for (int r = 0; r < 4; ++r) {
        int row = row0 + wm * 64 + mi * 16 + quad * 4 + r;
        int col = iBase + wn * 32 + nc * 16 + ml;
        float gg = g[r];
        float hv = 0.5f * gg * (1.f + erff(gg * 0.7071067811865475f)) * uu[r];
        h_buf[(size_t)row * I_DIM + col] = f2b(hv);
      }
    }
  }
}

// ---------------- GEMM2: y[slot] = h[slot] @ w2[e]^T (bf16 y, no atomics) --------
// 128 rows x 64 cols per block; wave owns 32 rows x 64 cols.
__global__ __launch_bounds__(256, 4) void k_gemm2(
    const unsigned short* __restrict__ h_buf,
    const unsigned short* __restrict__ w2b,
    const int* __restrict__ pad_off,
    unsigned short* __restrict__ y) {
  __shared__ __align__(16) unsigned short a_lds[128 * 64];
  __shared__ __align__(16) unsigned short b_lds[64 * 64];
  const int tid = threadIdx.x;
  const int wave = tid >> 6, lane = tid & 63;
  int rb, cb; swz_decode(blockIdx.x, rb, cb);
  const int row0 = rb * 128;
  if (row0 >= pad_off[E_NUM]) return;
  int e = 0;
#pragma unroll
  for (int i = 1; i < E_NUM; ++i) if (row0 >= pad_off[i]) e = i;
  const int cBase = cb * 64;
  const int srcChunk = (lane & 7) ^ ((lane >> 3) & 7);

  const unsigned short* agbase[4];
#pragma unroll
  for (int j = 0; j < 4; ++j) {
    int r = j * 32 + wave * 8 + (lane >> 3);
    agbase[j] = h_buf + (size_t)(row0 + r) * I_DIM + srcChunk * 8;
  }
  const unsigned short* bgbase[2];
#pragma unroll
  for (int j = 0; j < 2; ++j) {
    int brow = j * 32 + wave * 8 + (lane >> 3);
    bgbase[j] = w2b + ((size_t)e * H_DIM + cBase + brow) * I_DIM + srcChunk * 8;
  }
  f32x4 acc[2][4];
#pragma unroll
  for (int mi = 0; mi < 2; ++mi)
#pragma unroll
    for (int ni = 0; ni < 4; ++ni) acc[mi][ni] = (f32x4)(0.f);
  const int ml = lane & 15, quad = lane >> 4;

  for (int k0 = 0; k0 < I_DIM; k0 += 64) {
    __syncthreads();
#pragma unroll
    for (int j = 0; j < 4; ++j)
      async_copy16(agbase[j] + k0, a_lds + (j * 256 + wave * 64) * 8);
#pragma unroll
    for (int j = 0; j < 2; ++j)
      async_copy16(bgbase[j] + k0, b_lds + (j * 256 + wave * 64) * 8);
    __syncthreads();
#pragma unroll
    for (int ks = 0; ks < 2; ++ks) {
      const int ch = ((ks * 4 + quad) ^ (ml & 7)) * 8;
      bf16x8 af[2], bfr[4];
#pragma unroll
      for (int mi = 0; mi < 2; ++mi)
        af[mi] = *(const bf16x8*)(a_lds + (wave * 32 + mi * 16 + ml) * 64 + ch);
#pragma unroll
      for (int ni = 0; ni < 4; ++ni)
        bfr[ni] = *(const bf16x8*)(b_lds + (ni * 16 + ml) * 64 + ch);
#pragma unroll
      for (int mi = 0; mi < 2; ++mi)
#pragma unroll
        for (int ni = 0; ni < 4; ++ni)
          acc[mi][ni] = __builtin_amdgcn_mfma_f32_16x16x32_bf16(af[mi], bfr[ni], acc[mi][ni], 0, 0, 0);
    }
  }
#pragma unroll
  for (int mi = 0; mi < 2; ++mi) {
#pragma unroll
    for (int ni = 0; ni < 4; ++ni) {
#pragma unroll
      for (int r = 0; r < 4; ++r) {
        int row = row0 + wave * 32 + mi * 16 + quad * 4 + r;
        int col = cBase + ni * 16 + ml;
        y[(size_t)row * H_DIM + col] = f2b(acc[mi][ni][r]);
      }
    }
  }
}

// ---------------- combine: out[t] = cw0*y[slot0] + cw1*y[slot1] ----------------
__global__ void k_combine(const unsigned short* __restrict__ y,
                          const int* __restrict__ inv, const float* __restrict__ cw,
                          float* __restrict__ out) {
  const int t = blockIdx.x;
  const int c = threadIdx.x * 4;
  int s0 = inv[t * 2], s1 = inv[t * 2 + 1];
  float c0 = cw[t * 2], c1 = cw[t * 2 + 1];
  uint2 a = *(const uint2*)(y + (size_t)s0 * H_DIM + c);
  uint2 b = *(const uint2*)(y + (size_t)s1 * H_DIM + c);
  union { unsigned v; float f; } w;
  float4 o;
  float alo, ahi, blo, bhi;
  w.v = a.x << 16;          alo = w.f;
  w.v = a.x & 0xffff0000u;  ahi = w.f;
  w.v = b.x << 16;          blo = w.f;
  w.v = b.x & 0xffff0000u;  bhi = w.f;
  o.x = c0 * alo + c1 * blo;
  o.y = c0 * ahi + c1 * bhi;
  w.v = a.y << 16;          alo = w.f;
  w.v = a.y & 0xffff0000u;  ahi = w.f;
  w.v = b.y << 16;          blo = w.f;
  w.v = b.y & 0xffff0000u;  bhi = w.f;
  o.z = c0 * alo + c1 * blo;
  o.w = c0 * ahi + c1 * bhi;
  *(float4*)(out + (size_t)t * H_DIM + c) = o;
}

extern "C" void kernel_launch(void* const* d_in, const int* in_sizes, int n_in,
                              void* d_out, int out_size, void* d_ws, size_t ws_size,
                              hipStream_t stream) {
  const float* x      = (const float*)d_in[0];
  const float* logits = (const float*)d_in[1];
  const float* scale  = (const float*)d_in[2];
  const float* w13    = (const float*)d_in[3];
  const float* w2     = (const float*)d_in[4];
  float* out = (float*)d_out;

  char* ws = (char*)d_ws;
  int*   pad_off = (int*)(ws + 128);              // 9 ints
  float* cw      = (float*)(ws + 65536);          // T*2 floats (32 KB)
  int*   perm    = (int*)(ws + 131072);           // PAD_CAP ints (36 KB)
  int*   inv     = (int*)(ws + 196608);           // T*2 ints (32 KB)
  unsigned short* xb    = (unsigned short*)(ws + 0x40000);    // 8 MB
  unsigned short* h_buf = (unsigned short*)(ws + 0x900000);   // 18.9 MB
  unsigned short* w13b  = (unsigned short*)(ws + 0x1C00000);  // 32 MB (dead after gemm1)
  unsigned short* ybuf  = w13b;                                // overlay: 18.9 MB
  unsigned short* w2b   = (unsigned short*)(ws + 0x3C00000);  // 16 MB (total 76 MB; round-2
                                                              // PRE path proved ws >= 76 MB)

  k_route<<<1, 1024, 0, stream>>>(logits, scale, pad_off, perm, inv, cw);
  k_conv3<<<14336, 256, 0, stream>>>(x, w13, w2, xb, w13b, w2b);
  k_gemm1<<<1152, 256, 0, stream>>>(xb, w13b, perm, pad_off, h_buf);
  k_gemm2<<<1152, 256, 0, stream>>>(h_buf, w2b, pad_off, ybuf);
  k_combine<<<T_TOK, 256, 0, stream>>>(ybuf, inv, cw, out);
}

// Round 4
// 283.594 us; speedup vs baseline: 1.2871x; 1.0599x over previous
//
#include <hip/hip_runtime.h>
#include <hip/hip_bf16.h>

#define T_TOK 4096
#define H_DIM 1024
#define E_NUM 8
#define I_DIM 1024
#define PAD_CAP 9216   // 72 * 128 >= 8192 + 8*127

typedef __attribute__((ext_vector_type(4))) float f32x4;
typedef __attribute__((ext_vector_type(8))) short bf16x8;

__device__ __forceinline__ unsigned short f2b(float f) {
  union { float f; unsigned int u; } v; v.f = f;
  unsigned int r = v.u + 0x7fffu + ((v.u >> 16) & 1u);  // RNE to bf16
  return (unsigned short)(r >> 16);
}

__device__ __forceinline__ void async_copy16(const void* g, void* l) {
  __builtin_amdgcn_global_load_lds(
      (const __attribute__((address_space(1))) void*)g,
      (__attribute__((address_space(3))) void*)l, 16, 0, 0);
}

// ---------------- routing: one block does top2+softmax+histogram+scan+scatter+pad ----
__global__ __launch_bounds__(1024) void k_route(
    const float* __restrict__ logits, const float* __restrict__ scale,
    int* __restrict__ pad_off, int* __restrict__ perm,
    int* __restrict__ inv, float* __restrict__ cw) {
  __shared__ int s_cnt[E_NUM], s_off[E_NUM], s_cur[E_NUM];
  const int tid = threadIdx.x;
  if (tid < E_NUM) s_cnt[tid] = 0;
  __syncthreads();
  int e0[4], e1[4];
#pragma unroll
  for (int it = 0; it < 4; ++it) {
    int t = it * 1024 + tid;
    float l[E_NUM];
    *(float4*)(l)     = *(const float4*)(logits + (size_t)t * E_NUM);
    *(float4*)(l + 4) = *(const float4*)(logits + (size_t)t * E_NUM + 4);
    float m = l[0];
#pragma unroll
    for (int i = 1; i < E_NUM; ++i) m = fmaxf(m, l[i]);
    float p[E_NUM]; float s = 0.f;
#pragma unroll
    for (int i = 0; i < E_NUM; ++i) { p[i] = expf(l[i] - m); s += p[i]; }
    int i0 = 0; float b0 = l[0];
#pragma unroll
    for (int i = 1; i < E_NUM; ++i) if (l[i] > b0) { b0 = l[i]; i0 = i; }
    int i1 = -1; float b1 = -1e30f;
#pragma unroll
    for (int i = 0; i < E_NUM; ++i) if (i != i0 && l[i] > b1) { b1 = l[i]; i1 = i; }
    float g0 = p[i0] / s, g1 = p[i1] / s;
    float r = g0 + g1;
    cw[t * 2]     = g0 / r * scale[i0];
    cw[t * 2 + 1] = g1 / r * scale[i1];
    e0[it] = i0; e1[it] = i1;
    atomicAdd(&s_cnt[i0], 1);
    atomicAdd(&s_cnt[i1], 1);
  }
  __syncthreads();
  if (tid == 0) {
    int off = 0;
    for (int e = 0; e < E_NUM; ++e) {
      s_off[e] = off; s_cur[e] = off; pad_off[e] = off;
      off += (s_cnt[e] + 127) & ~127;
    }
    pad_off[E_NUM] = off;
  }
  __syncthreads();
#pragma unroll
  for (int it = 0; it < 4; ++it) {
    int t = it * 1024 + tid;
    int sl0 = atomicAdd(&s_cur[e0[it]], 1);
    perm[sl0] = t * 2;     inv[t * 2] = sl0;
    int sl1 = atomicAdd(&s_cur[e1[it]], 1);
    perm[sl1] = t * 2 + 1; inv[t * 2 + 1] = sl1;
  }
  __syncthreads();  // s_cur[e] == s_off[e] + s_cnt[e] now
  for (int e = 0; e < E_NUM; ++e) {
    int start = s_off[e] + s_cnt[e];
    int end   = s_off[e] + ((s_cnt[e] + 127) & ~127);
    for (int i = start + tid; i < end; i += 1024) perm[i] = -1;
  }
}

// ---------------- fused f32 -> bf16 for x, w13, w2 (2048 elems/block) ----------------
__global__ void k_conv3(const float* __restrict__ x, const float* __restrict__ w13,
                        const float* __restrict__ w2,
                        unsigned short* __restrict__ xb,
                        unsigned short* __restrict__ w13b,
                        unsigned short* __restrict__ w2b) {
  int b = blockIdx.x;
  const float* src; unsigned short* dst; size_t base;
  if (b < 2048)       { src = x;   dst = xb;   base = (size_t)b * 2048; }
  else if (b < 10240) { src = w13; dst = w13b; base = (size_t)(b - 2048) * 2048; }
  else                { src = w2;  dst = w2b;  base = (size_t)(b - 10240) * 2048; }
  size_t i = base + (size_t)threadIdx.x * 8;
  float4 f0 = *(const float4*)(src + i);
  float4 f1 = *(const float4*)(src + i + 4);
  uint4 pk;
  pk.x = (unsigned)f2b(f0.x) | ((unsigned)f2b(f0.y) << 16);
  pk.y = (unsigned)f2b(f0.z) | ((unsigned)f2b(f0.w) << 16);
  pk.z = (unsigned)f2b(f1.x) | ((unsigned)f2b(f1.y) << 16);
  pk.w = (unsigned)f2b(f1.z) | ((unsigned)f2b(f1.w) << 16);
  *(uint4*)(dst + i) = pk;
}

// ---------------- GEMM1: h = gelu(x@w1^T) * (x@w3^T) ----------------
// Grid dim3(16, 72), blockIdx.x = col-block (FAST). With round-robin block->XCD
// dispatch this pins cb -> XCD (x%8): each (expert, cb) w13 slice (256 KB) stays
// resident in one XCD's L2 across all row-blocks of the expert. Do NOT swizzle
// blockIdx — round-3's rb-affine swizzle thrashed L2 (FETCH 194 MB, 2x slower).
// 128 padded rows x 64 unique i-cols (128 MFMA cols: 64 w1-rows ++ 64 w3-rows
// interleaved in 32-row segments). Wave (wm,wn) 2x2; ni 0,1 = g, ni 2,3 = u.
__global__ __launch_bounds__(256, 4) void k_gemm1(
    const unsigned short* __restrict__ xbf,
    const unsigned short* __restrict__ w13b,
    const int* __restrict__ perm, const int* __restrict__ pad_off,
    unsigned short* __restrict__ h_buf) {
  __shared__ __align__(16) unsigned short a_lds[128 * 64];
  __shared__ __align__(16) unsigned short b_lds[128 * 64];
  const int tid = threadIdx.x;
  const int wave = tid >> 6, lane = tid & 63;
  const int row0 = blockIdx.y * 128;
  if (row0 >= pad_off[E_NUM]) return;
  int e = 0;
#pragma unroll
  for (int i = 1; i < E_NUM; ++i) if (row0 >= pad_off[i]) e = i;
  const int iBase = blockIdx.x * 64;

  const int srcChunk = (lane & 7) ^ ((lane >> 3) & 7);

  const unsigned short* agbase[4];
#pragma unroll
  for (int j = 0; j < 4; ++j) {
    int r = j * 32 + wave * 8 + (lane >> 3);
    int p = perm[row0 + r];
    int tok = (p < 0) ? 0 : (p >> 1);
    agbase[j] = xbf + (size_t)tok * H_DIM + srcChunk * 8;
  }
  const unsigned short* bgbase[4];
#pragma unroll
  for (int j = 0; j < 4; ++j) {
    int brow = j * 32 + wave * 8 + (lane >> 3);
    int seg = brow >> 5, half = seg & 1;
    int col = iBase + (seg >> 1) * 32 + (brow & 31);
    bgbase[j] = w13b + ((size_t)e * 2 * I_DIM + half * I_DIM + col) * H_DIM + srcChunk * 8;
  }

  f32x4 acc[4][4];
#pragma unroll
  for (int mi = 0; mi < 4; ++mi)
#pragma unroll
    for (int ni = 0; ni < 4; ++ni) acc[mi][ni] = (f32x4)(0.f);

  const int wm = wave >> 1, wn = wave & 1;
  const int ml = lane & 15, quad = lane >> 4;

  for (int k0 = 0; k0 < H_DIM; k0 += 64) {
    __syncthreads();
#pragma unroll
    for (int j = 0; j < 4; ++j)
      async_copy16(agbase[j] + k0, a_lds + (j * 256 + wave * 64) * 8);
#pragma unroll
    for (int j = 0; j < 4; ++j)
      async_copy16(bgbase[j] + k0, b_lds + (j * 256 + wave * 64) * 8);
    __syncthreads();
#pragma unroll
    for (int ks = 0; ks < 2; ++ks) {
      const int ch = ((ks * 4 + quad) ^ (ml & 7)) * 8;
      bf16x8 af[4], bfr[4];
#pragma unroll
      for (int mi = 0; mi < 4; ++mi)
        af[mi] = *(const bf16x8*)(a_lds + (wm * 64 + mi * 16 + ml) * 64 + ch);
#pragma unroll
      for (int ni = 0; ni < 4; ++ni)
        bfr[ni] = *(const bf16x8*)(b_lds + (wn * 64 + ni * 16 + ml) * 64 + ch);
#pragma unroll
      for (int mi = 0; mi < 4; ++mi)
#pragma unroll
        for (int ni = 0; ni < 4; ++ni)
          acc[mi][ni] = __builtin_amdgcn_mfma_f32_16x16x32_bf16(af[mi], bfr[ni], acc[mi][ni], 0, 0, 0);
    }
  }
#pragma unroll
  for (int mi = 0; mi < 4; ++mi) {
#pragma unroll
    for (int nc = 0; nc < 2; ++nc) {
      f32x4 g = acc[mi][nc];
      f32x4 uu = acc[mi][nc + 2];
#pragma unroll
      for (int r = 0; r < 4; ++r) {
        int row = row0 + wm * 64 + mi * 16 + quad * 4 + r;
        int col = iBase + wn * 32 + nc * 16 + ml;
        float gg = g[r];
        float hv = 0.5f * gg * (1.f + erff(gg * 0.7071067811865475f)) * uu[r];
        h_buf[(size_t)row * I_DIM + col] = f2b(hv);
      }
    }
  }
}

// ---------------- GEMM2: y[slot] = h[slot] @ w2[e]^T (bf16 y, no atomics) --------
// Grid dim3(16, 72), col-fast (same XCD-affinity argument as gemm1).
// 128 rows x 64 cols per block; wave owns 32 rows x 64 cols.
__global__ __launch_bounds__(256, 4) void k_gemm2(
    const unsigned short* __restrict__ h_buf,
    const unsigned short* __restrict__ w2b,
    const int* __restrict__ pad_off,
    unsigned short* __restrict__ y) {
  __shared__ __align__(16) unsigned short a_lds[128 * 64];
  __shared__ __align__(16) unsigned short b_lds[64 * 64];
  const int tid = threadIdx.x;
  const int wave = tid >> 6, lane = tid & 63;
  const int row0 = blockIdx.y * 128;
  if (row0 >= pad_off[E_NUM]) return;
  int e = 0;
#pragma unroll
  for (int i = 1; i < E_NUM; ++i) if (row0 >= pad_off[i]) e = i;
  const int cBase = blockIdx.x * 64;
  const int srcChunk = (lane & 7) ^ ((lane >> 3) & 7);

  const unsigned short* agbase[4];
#pragma unroll
  for (int j = 0; j < 4; ++j) {
    int r = j * 32 + wave * 8 + (lane >> 3);
    agbase[j] = h_buf + (size_t)(row0 + r) * I_DIM + srcChunk * 8;
  }
  const unsigned short* bgbase[2];
#pragma unroll
  for (int j = 0; j < 2; ++j) {
    int brow = j * 32 + wave * 8 + (lane >> 3);
    bgbase[j] = w2b + ((size_t)e * H_DIM + cBase + brow) * I_DIM + srcChunk * 8;
  }
  f32x4 acc[2][4];
#pragma unroll
  for (int mi = 0; mi < 2; ++mi)
#pragma unroll
    for (int ni = 0; ni < 4; ++ni) acc[mi][ni] = (f32x4)(0.f);
  const int ml = lane & 15, quad = lane >> 4;

  for (int k0 = 0; k0 < I_DIM; k0 += 64) {
    __syncthreads();
#pragma unroll
    for (int j = 0; j < 4; ++j)
      async_copy16(agbase[j] + k0, a_lds + (j * 256 + wave * 64) * 8);
#pragma unroll
    for (int j = 0; j < 2; ++j)
      async_copy16(bgbase[j] + k0, b_lds + (j * 256 + wave * 64) * 8);
    __syncthreads();
#pragma unroll
    for (int ks = 0; ks < 2; ++ks) {
      const int ch = ((ks * 4 + quad) ^ (ml & 7)) * 8;
      bf16x8 af[2], bfr[4];
#pragma unroll
      for (int mi = 0; mi < 2; ++mi)
        af[mi] = *(const bf16x8*)(a_lds + (wave * 32 + mi * 16 + ml) * 64 + ch);
#pragma unroll
      for (int ni = 0; ni < 4; ++ni)
        bfr[ni] = *(const bf16x8*)(b_lds + (ni * 16 + ml) * 64 + ch);
#pragma unroll
      for (int mi = 0; mi < 2; ++mi)
#pragma unroll
        for (int ni = 0; ni < 4; ++ni)
          acc[mi][ni] = __builtin_amdgcn_mfma_f32_16x16x32_bf16(af[mi], bfr[ni], acc[mi][ni], 0, 0, 0);
    }
  }
#pragma unroll
  for (int mi = 0; mi < 2; ++mi) {
#pragma unroll
    for (int ni = 0; ni < 4; ++ni) {
#pragma unroll
      for (int r = 0; r < 4; ++r) {
        int row = row0 + wave * 32 + mi * 16 + quad * 4 + r;
        int col = cBase + ni * 16 + ml;
        y[(size_t)row * H_DIM + col] = f2b(acc[mi][ni][r]);
      }
    }
  }
}

// ---------------- combine: out[t] = cw0*y[slot0] + cw1*y[slot1] ----------------
__global__ void k_combine(const unsigned short* __restrict__ y,
                          const int* __restrict__ inv, const float* __restrict__ cw,
                          float* __restrict__ out) {
  const int t = blockIdx.x;
  const int c = threadIdx.x * 4;
  int s0 = inv[t * 2], s1 = inv[t * 2 + 1];
  float c0 = cw[t * 2], c1 = cw[t * 2 + 1];
  uint2 a = *(const uint2*)(y + (size_t)s0 * H_DIM + c);
  uint2 b = *(const uint2*)(y + (size_t)s1 * H_DIM + c);
  union { unsigned v; float f; } w;
  float4 o;
  float alo, ahi, blo, bhi;
  w.v = a.x << 16;          alo = w.f;
  w.v = a.x & 0xffff0000u;  ahi = w.f;
  w.v = b.x << 16;          blo = w.f;
  w.v = b.x & 0xffff0000u;  bhi = w.f;
  o.x = c0 * alo + c1 * blo;
  o.y = c0 * ahi + c1 * bhi;
  w.v = a.y << 16;          alo = w.f;
  w.v = a.y & 0xffff0000u;  ahi = w.f;
  w.v = b.y << 16;          blo = w.f;
  w.v = b.y & 0xffff0000u;  bhi = w.f;
  o.z = c0 * alo + c1 * blo;
  o.w = c0 * ahi + c1 * bhi;
  *(float4*)(out + (size_t)t * H_DIM + c) = o;
}

extern "C" void kernel_launch(void* const* d_in, const int* in_sizes, int n_in,
                              void* d_out, int out_size, void* d_ws, size_t ws_size,
                              hipStream_t stream) {
  const float* x      = (const float*)d_in[0];
  const float* logits = (const float*)d_in[1];
  const float* scale  = (const float*)d_in[2];
  const float* w13    = (const float*)d_in[3];
  const float* w2     = (const float*)d_in[4];
  float* out = (float*)d_out;

  char* ws = (char*)d_ws;
  int*   pad_off = (int*)(ws + 128);              // 9 ints
  float* cw      = (float*)(ws + 65536);          // T*2 floats (32 KB)
  int*   perm    = (int*)(ws + 131072);           // PAD_CAP ints (36 KB)
  int*   inv     = (int*)(ws + 196608);           // T*2 ints (32 KB)
  unsigned short* xb    = (unsigned short*)(ws + 0x40000);    // 8 MB
  unsigned short* h_buf = (unsigned short*)(ws + 0x900000);   // 18.9 MB
  unsigned short* w13b  = (unsigned short*)(ws + 0x1C00000);  // 32 MB (dead after gemm1)
  unsigned short* ybuf  = w13b;                                // overlay: 18.9 MB
  unsigned short* w2b   = (unsigned short*)(ws + 0x3C00000);  // 16 MB (total 76 MB)

  k_route<<<1, 1024, 0, stream>>>(logits, scale, pad_off, perm, inv, cw);
  k_conv3<<<14336, 256, 0, stream>>>(x, w13, w2, xb, w13b, w2b);
  k_gemm1<<<dim3(16, PAD_CAP / 128), 256, 0, stream>>>(xb, w13b, perm, pad_off, h_buf);
  k_gemm2<<<dim3(16, PAD_CAP / 128), 256, 0, stream>>>(h_buf, w2b, pad_off, ybuf);
  k_combine<<<T_TOK, 256, 0, stream>>>(ybuf, inv, cw, out);
}

// Round 5
// 246.275 us; speedup vs baseline: 1.4821x; 1.1515x over previous
//
#include <hip/hip_runtime.h>
#include <hip/hip_bf16.h>

#define T_TOK 4096
#define H_DIM 1024
#define E_NUM 8
#define I_DIM 1024
#define PAD_CAP 9216   // 72 * 128 >= 8192 + 8*127

typedef __attribute__((ext_vector_type(4))) float f32x4;
typedef __attribute__((ext_vector_type(8))) short bf16x8;

__device__ __forceinline__ unsigned short f2b(float f) {
  union { float f; unsigned int u; } v; v.f = f;
  unsigned int r = v.u + 0x7fffu + ((v.u >> 16) & 1u);  // RNE to bf16
  return (unsigned short)(r >> 16);
}

__device__ __forceinline__ void async_copy16(const void* g, void* l) {
  __builtin_amdgcn_global_load_lds(
      (const __attribute__((address_space(1))) void*)g,
      (__attribute__((address_space(3))) void*)l, 16, 0, 0);
}

// ---------------- routing: one block does top2+softmax+histogram+scan+scatter+pad ----
__global__ __launch_bounds__(1024) void k_route(
    const float* __restrict__ logits, const float* __restrict__ scale,
    int* __restrict__ pad_off, int* __restrict__ perm,
    int* __restrict__ inv, float* __restrict__ cw) {
  __shared__ int s_cnt[E_NUM], s_off[E_NUM], s_cur[E_NUM];
  const int tid = threadIdx.x;
  if (tid < E_NUM) s_cnt[tid] = 0;
  __syncthreads();
  int e0[4], e1[4];
#pragma unroll
  for (int it = 0; it < 4; ++it) {
    int t = it * 1024 + tid;
    float l[E_NUM];
    *(float4*)(l)     = *(const float4*)(logits + (size_t)t * E_NUM);
    *(float4*)(l + 4) = *(const float4*)(logits + (size_t)t * E_NUM + 4);
    float m = l[0];
#pragma unroll
    for (int i = 1; i < E_NUM; ++i) m = fmaxf(m, l[i]);
    float p[E_NUM]; float s = 0.f;
#pragma unroll
    for (int i = 0; i < E_NUM; ++i) { p[i] = expf(l[i] - m); s += p[i]; }
    int i0 = 0; float b0 = l[0];
#pragma unroll
    for (int i = 1; i < E_NUM; ++i) if (l[i] > b0) { b0 = l[i]; i0 = i; }
    int i1 = -1; float b1 = -1e30f;
#pragma unroll
    for (int i = 0; i < E_NUM; ++i) if (i != i0 && l[i] > b1) { b1 = l[i]; i1 = i; }
    float g0 = p[i0] / s, g1 = p[i1] / s;
    float r = g0 + g1;
    cw[t * 2]     = g0 / r * scale[i0];
    cw[t * 2 + 1] = g1 / r * scale[i1];
    e0[it] = i0; e1[it] = i1;
    atomicAdd(&s_cnt[i0], 1);
    atomicAdd(&s_cnt[i1], 1);
  }
  __syncthreads();
  if (tid == 0) {
    int off = 0;
    for (int e = 0; e < E_NUM; ++e) {
      s_off[e] = off; s_cur[e] = off; pad_off[e] = off;
      off += (s_cnt[e] + 127) & ~127;
    }
    pad_off[E_NUM] = off;
  }
  __syncthreads();
#pragma unroll
  for (int it = 0; it < 4; ++it) {
    int t = it * 1024 + tid;
    int sl0 = atomicAdd(&s_cur[e0[it]], 1);
    perm[sl0] = t * 2;     inv[t * 2] = sl0;
    int sl1 = atomicAdd(&s_cur[e1[it]], 1);
    perm[sl1] = t * 2 + 1; inv[t * 2 + 1] = sl1;
  }
  __syncthreads();  // s_cur[e] == s_off[e] + s_cnt[e] now
  for (int e = 0; e < E_NUM; ++e) {
    int start = s_off[e] + s_cnt[e];
    int end   = s_off[e] + ((s_cnt[e] + 127) & ~127);
    for (int i = start + tid; i < end; i += 1024) perm[i] = -1;
  }
}

// ---------------- fused f32 -> bf16 for x, w13, w2 (2048 elems/block) ----------------
__global__ void k_conv3(const float* __restrict__ x, const float* __restrict__ w13,
                        const float* __restrict__ w2,
                        unsigned short* __restrict__ xb,
                        unsigned short* __restrict__ w13b,
                        unsigned short* __restrict__ w2b) {
  int b = blockIdx.x;
  const float* src; unsigned short* dst; size_t base;
  if (b < 2048)       { src = x;   dst = xb;   base = (size_t)b * 2048; }
  else if (b < 10240) { src = w13; dst = w13b; base = (size_t)(b - 2048) * 2048; }
  else                { src = w2;  dst = w2b;  base = (size_t)(b - 10240) * 2048; }
  size_t i = base + (size_t)threadIdx.x * 8;
  float4 f0 = *(const float4*)(src + i);
  float4 f1 = *(const float4*)(src + i + 4);
  uint4 pk;
  pk.x = (unsigned)f2b(f0.x) | ((unsigned)f2b(f0.y) << 16);
  pk.y = (unsigned)f2b(f0.z) | ((unsigned)f2b(f0.w) << 16);
  pk.z = (unsigned)f2b(f1.x) | ((unsigned)f2b(f1.y) << 16);
  pk.w = (unsigned)f2b(f1.z) | ((unsigned)f2b(f1.w) << 16);
  *(uint4*)(dst + i) = pk;
}

// ---------------- GEMM1: h = gelu(x@w1^T) * (x@w3^T) ----------------
// Grid dim3(16, 72), blockIdx.x = col-block (FAST): round-robin dispatch pins
// cb -> XCD, so each (expert, cb) w13 slice stays in one XCD's L2. Do NOT
// swizzle blockIdx (round 3: FETCH 194 MB, 2x slower).
// __launch_bounds__(256, 2): LDS (64 KB) caps residency at 2 blocks/CU, so
// asking for more (round 3/4's (256,4)) only squeezes VGPRs 72->64 and loses
// K-loop latency-hiding ILP — measured 55 -> 94 us regression. Keep at 2.
// 128 padded rows x 64 unique i-cols (128 MFMA cols: 64 w1 ++ 64 w3 rows
// interleaved in 32-row segments). Wave (wm,wn) 2x2; ni 0,1 = g, ni 2,3 = u.
__global__ __launch_bounds__(256, 2) void k_gemm1(
    const unsigned short* __restrict__ xbf,
    const unsigned short* __restrict__ w13b,
    const int* __restrict__ perm, const int* __restrict__ pad_off,
    unsigned short* __restrict__ h_buf) {
  __shared__ __align__(16) unsigned short a_lds[128 * 64];
  __shared__ __align__(16) unsigned short b_lds[128 * 64];
  const int tid = threadIdx.x;
  const int wave = tid >> 6, lane = tid & 63;
  const int row0 = blockIdx.y * 128;
  if (row0 >= pad_off[E_NUM]) return;
  int e = 0;
#pragma unroll
  for (int i = 1; i < E_NUM; ++i) if (row0 >= pad_off[i]) e = i;
  const int iBase = blockIdx.x * 64;

  const int srcChunk = (lane & 7) ^ ((lane >> 3) & 7);

  const unsigned short* agbase[4];
#pragma unroll
  for (int j = 0; j < 4; ++j) {
    int r = j * 32 + wave * 8 + (lane >> 3);
    int p = perm[row0 + r];
    int tok = (p < 0) ? 0 : (p >> 1);
    agbase[j] = xbf + (size_t)tok * H_DIM + srcChunk * 8;
  }
  const unsigned short* bgbase[4];
#pragma unroll
  for (int j = 0; j < 4; ++j) {
    int brow = j * 32 + wave * 8 + (lane >> 3);
    int seg = brow >> 5, half = seg & 1;
    int col = iBase + (seg >> 1) * 32 + (brow & 31);
    bgbase[j] = w13b + ((size_t)e * 2 * I_DIM + half * I_DIM + col) * H_DIM + srcChunk * 8;
  }

  f32x4 acc[4][4];
#pragma unroll
  for (int mi = 0; mi < 4; ++mi)
#pragma unroll
    for (int ni = 0; ni < 4; ++ni) acc[mi][ni] = (f32x4)(0.f);

  const int wm = wave >> 1, wn = wave & 1;
  const int ml = lane & 15, quad = lane >> 4;

  for (int k0 = 0; k0 < H_DIM; k0 += 64) {
    __syncthreads();
#pragma unroll
    for (int j = 0; j < 4; ++j)
      async_copy16(agbase[j] + k0, a_lds + (j * 256 + wave * 64) * 8);
#pragma unroll
    for (int j = 0; j < 4; ++j)
      async_copy16(bgbase[j] + k0, b_lds + (j * 256 + wave * 64) * 8);
    __syncthreads();
#pragma unroll
    for (int ks = 0; ks < 2; ++ks) {
      const int ch = ((ks * 4 + quad) ^ (ml & 7)) * 8;
      bf16x8 af[4], bfr[4];
#pragma unroll
      for (int mi = 0; mi < 4; ++mi)
        af[mi] = *(const bf16x8*)(a_lds + (wm * 64 + mi * 16 + ml) * 64 + ch);
#pragma unroll
      for (int ni = 0; ni < 4; ++ni)
        bfr[ni] = *(const bf16x8*)(b_lds + (wn * 64 + ni * 16 + ml) * 64 + ch);
#pragma unroll
      for (int mi = 0; mi < 4; ++mi)
#pragma unroll
        for (int ni = 0; ni < 4; ++ni)
          acc[mi][ni] = __builtin_amdgcn_mfma_f32_16x16x32_bf16(af[mi], bfr[ni], acc[mi][ni], 0, 0, 0);
    }
  }
#pragma unroll
  for (int mi = 0; mi < 4; ++mi) {
#pragma unroll
    for (int nc = 0; nc < 2; ++nc) {
      f32x4 g = acc[mi][nc];
      f32x4 uu = acc[mi][nc + 2];
#pragma unroll
      for (int r = 0; r < 4; ++r) {
        int row = row0 + wm * 64 + mi * 16 + quad * 4 + r;
        int col = iBase + wn * 32 + nc * 16 + ml;
        float gg = g[r];
        float hv = 0.5f * gg * (1.f + erff(gg * 0.7071067811865475f)) * uu[r];
        h_buf[(size_t)row * I_DIM + col] = f2b(hv);
      }
    }
  }
}

// ---------------- GEMM2: y[slot] = h[slot] @ w2[e]^T (bf16 y, no atomics) --------
// Grid dim3(16, 72), col-fast (same XCD-affinity argument as gemm1).
// 128 rows x 64 cols per block; wave owns 32 rows x 64 cols. 24.6 KB LDS ->
// up to 6 blocks/CU; __launch_bounds__(256,2) leaves the allocator free
// (VGPR ~72 still admits 6 blocks; don't repeat the (256,4) squeeze).
__global__ __launch_bounds__(256, 2) void k_gemm2(
    const unsigned short* __restrict__ h_buf,
    const unsigned short* __restrict__ w2b,
    const int* __restrict__ pad_off,
    unsigned short* __restrict__ y) {
  __shared__ __align__(16) unsigned short a_lds[128 * 64];
  __shared__ __align__(16) unsigned short b_lds[64 * 64];
  const int tid = threadIdx.x;
  const int wave = tid >> 6, lane = tid & 63;
  const int row0 = blockIdx.y * 128;
  if (row0 >= pad_off[E_NUM]) return;
  int e = 0;
#pragma unroll
  for (int i = 1; i < E_NUM; ++i) if (row0 >= pad_off[i]) e = i;
  const int cBase = blockIdx.x * 64;
  const int srcChunk = (lane & 7) ^ ((lane >> 3) & 7);

  const unsigned short* agbase[4];
#pragma unroll
  for (int j = 0; j < 4; ++j) {
    int r = j * 32 + wave * 8 + (lane >> 3);
    agbase[j] = h_buf + (size_t)(row0 + r) * I_DIM + srcChunk * 8;
  }
  const unsigned short* bgbase[2];
#pragma unroll
  for (int j = 0; j < 2; ++j) {
    int brow = j * 32 + wave * 8 + (lane >> 3);
    bgbase[j] = w2b + ((size_t)e * H_DIM + cBase + brow) * I_DIM + srcChunk * 8;
  }
  f32x4 acc[2][4];
#pragma unroll
  for (int mi = 0; mi < 2; ++mi)
#pragma unroll
    for (int ni = 0; ni < 4; ++ni) acc[mi][ni] = (f32x4)(0.f);
  const int ml = lane & 15, quad = lane >> 4;

  for (int k0 = 0; k0 < I_DIM; k0 += 64) {
    __syncthreads();
#pragma unroll
    for (int j = 0; j < 4; ++j)
      async_copy16(agbase[j] + k0, a_lds + (j * 256 + wave * 64) * 8);
#pragma unroll
    for (int j = 0; j < 2; ++j)
      async_copy16(bgbase[j] + k0, b_lds + (j * 256 + wave * 64) * 8);
    __syncthreads();
#pragma unroll
    for (int ks = 0; ks < 2; ++ks) {
      const int ch = ((ks * 4 + quad) ^ (ml & 7)) * 8;
      bf16x8 af[2], bfr[4];
#pragma unroll
      for (int mi = 0; mi < 2; ++mi)
        af[mi] = *(const bf16x8*)(a_lds + (wave * 32 + mi * 16 + ml) * 64 + ch);
#pragma unroll
      for (int ni = 0; ni < 4; ++ni)
        bfr[ni] = *(const bf16x8*)(b_lds + (ni * 16 + ml) * 64 + ch);
#pragma unroll
      for (int mi = 0; mi < 2; ++mi)
#pragma unroll
        for (int ni = 0; ni < 4; ++ni)
          acc[mi][ni] = __builtin_amdgcn_mfma_f32_16x16x32_bf16(af[mi], bfr[ni], acc[mi][ni], 0, 0, 0);
    }
  }
#pragma unroll
  for (int mi = 0; mi < 2; ++mi) {
#pragma unroll
    for (int ni = 0; ni < 4; ++ni) {
#pragma unroll
      for (int r = 0; r < 4; ++r) {
        int row = row0 + wave * 32 + mi * 16 + quad * 4 + r;
        int col = cBase + ni * 16 + ml;
        y[(size_t)row * H_DIM + col] = f2b(acc[mi][ni][r]);
      }
    }
  }
}

// ---------------- combine: out[t] = cw0*y[slot0] + cw1*y[slot1] ----------------
__global__ void k_combine(const unsigned short* __restrict__ y,
                          const int* __restrict__ inv, const float* __restrict__ cw,
                          float* __restrict__ out) {
  const int t = blockIdx.x;
  const int c = threadIdx.x * 4;
  int s0 = inv[t * 2], s1 = inv[t * 2 + 1];
  float c0 = cw[t * 2], c1 = cw[t * 2 + 1];
  uint2 a = *(const uint2*)(y + (size_t)s0 * H_DIM + c);
  uint2 b = *(const uint2*)(y + (size_t)s1 * H_DIM + c);
  union { unsigned v; float f; } w;
  float4 o;
  float alo, ahi, blo, bhi;
  w.v = a.x << 16;          alo = w.f;
  w.v = a.x & 0xffff0000u;  ahi = w.f;
  w.v = b.x << 16;          blo = w.f;
  w.v = b.x & 0xffff0000u;  bhi = w.f;
  o.x = c0 * alo + c1 * blo;
  o.y = c0 * ahi + c1 * bhi;
  w.v = a.y << 16;          alo = w.f;
  w.v = a.y & 0xffff0000u;  ahi = w.f;
  w.v = b.y << 16;          blo = w.f;
  w.v = b.y & 0xffff0000u;  bhi = w.f;
  o.z = c0 * alo + c1 * blo;
  o.w = c0 * ahi + c1 * bhi;
  *(float4*)(out + (size_t)t * H_DIM + c) = o;
}

extern "C" void kernel_launch(void* const* d_in, const int* in_sizes, int n_in,
                              void* d_out, int out_size, void* d_ws, size_t ws_size,
                              hipStream_t stream) {
  const float* x      = (const float*)d_in[0];
  const float* logits = (const float*)d_in[1];
  const float* scale  = (const float*)d_in[2];
  const float* w13    = (const float*)d_in[3];
  const float* w2     = (const float*)d_in[4];
  float* out = (float*)d_out;

  char* ws = (char*)d_ws;
  int*   pad_off = (int*)(ws + 128);              // 9 ints
  float* cw      = (float*)(ws + 65536);          // T*2 floats (32 KB)
  int*   perm    = (int*)(ws + 131072);           // PAD_CAP ints (36 KB)
  int*   inv     = (int*)(ws + 196608);           // T*2 ints (32 KB)
  unsigned short* xb    = (unsigned short*)(ws + 0x40000);    // 8 MB
  unsigned short* h_buf = (unsigned short*)(ws + 0x900000);   // 18.9 MB
  unsigned short* w13b  = (unsigned short*)(ws + 0x1C00000);  // 32 MB (dead after gemm1)
  unsigned short* ybuf  = w13b;                                // overlay: 18.9 MB
  unsigned short* w2b   = (unsigned short*)(ws + 0x3C00000);  // 16 MB (total 76 MB)

  k_route<<<1, 1024, 0, stream>>>(logits, scale, pad_off, perm, inv, cw);
  k_conv3<<<14336, 256, 0, stream>>>(x, w13, w2, xb, w13b, w2b);
  k_gemm1<<<dim3(16, PAD_CAP / 128), 256, 0, stream>>>(xb, w13b, perm, pad_off, h_buf);
  k_gemm2<<<dim3(16, PAD_CAP / 128), 256, 0, stream>>>(h_buf, w2b, pad_off, ybuf);
  k_combine<<<T_TOK, 256, 0, stream>>>(ybuf, inv, cw, out);
}

// Round 6
// 241.830 us; speedup vs baseline: 1.5093x; 1.0184x over previous
//
#include <hip/hip_runtime.h>
#include <hip/hip_bf16.h>

#define T_TOK 4096
#define H_DIM 1024
#define E_NUM 8
#define I_DIM 1024
#define PAD_CAP 9216   // 72 * 128 >= 8192 + 8*127
#define RBLK 16        // router blocks (256 tokens each)

typedef __attribute__((ext_vector_type(4))) float f32x4;
typedef __attribute__((ext_vector_type(8))) short bf16x8;

__device__ __forceinline__ unsigned short f2b(float f) {
  union { float f; unsigned int u; } v; v.f = f;
  unsigned int r = v.u + 0x7fffu + ((v.u >> 16) & 1u);  // RNE to bf16
  return (unsigned short)(r >> 16);
}

__device__ __forceinline__ void async_copy16(const void* g, void* l) {
  __builtin_amdgcn_global_load_lds(
      (const __attribute__((address_space(1))) void*)g,
      (__attribute__((address_space(3))) void*)l, 16, 0, 0);
}

// ---------------- prep: blocks 0..15 route-count, 16..14351 f32->bf16 conv ------
// Routing runs on 16 blocks (parallel, LDS-only atomics) and its latency hides
// under the BW-bound conversion. Per-block counts are written NON-atomically to
// cnt[16][8]; k_scan turns them into exact slot bases (no global atomics ever).
__global__ __launch_bounds__(256) void k_prep(
    const float* __restrict__ x, const float* __restrict__ logits,
    const float* __restrict__ scale,
    const float* __restrict__ w13, const float* __restrict__ w2,
    unsigned short* __restrict__ xb, unsigned short* __restrict__ w13b,
    unsigned short* __restrict__ w2b,
    int* __restrict__ tids, float* __restrict__ cw, int* __restrict__ cnt) {
  const int b = blockIdx.x;
  if (b < RBLK) {
    __shared__ int s_cnt[E_NUM];
    const int tid = threadIdx.x;
    if (tid < E_NUM) s_cnt[tid] = 0;
    __syncthreads();
    int t = b * 256 + tid;
    float l[E_NUM];
    *(float4*)(l)     = *(const float4*)(logits + (size_t)t * E_NUM);
    *(float4*)(l + 4) = *(const float4*)(logits + (size_t)t * E_NUM + 4);
    float m = l[0];
#pragma unroll
    for (int i = 1; i < E_NUM; ++i) m = fmaxf(m, l[i]);
    float p[E_NUM]; float s = 0.f;
#pragma unroll
    for (int i = 0; i < E_NUM; ++i) { p[i] = expf(l[i] - m); s += p[i]; }
    int i0 = 0; float b0 = l[0];
#pragma unroll
    for (int i = 1; i < E_NUM; ++i) if (l[i] > b0) { b0 = l[i]; i0 = i; }
    int i1 = -1; float b1 = -1e30f;
#pragma unroll
    for (int i = 0; i < E_NUM; ++i) if (i != i0 && l[i] > b1) { b1 = l[i]; i1 = i; }
    float g0 = p[i0] / s, g1 = p[i1] / s;
    float r = g0 + g1;
    cw[t * 2]     = g0 / r * scale[i0];
    cw[t * 2 + 1] = g1 / r * scale[i1];
    tids[t * 2] = i0; tids[t * 2 + 1] = i1;
    atomicAdd(&s_cnt[i0], 1);
    atomicAdd(&s_cnt[i1], 1);
    __syncthreads();
    if (tid < E_NUM) cnt[b * E_NUM + tid] = s_cnt[tid];
    return;
  }
  const int cb = b - RBLK;
  const float* src; unsigned short* dst; size_t base;
  if (cb < 2048)       { src = x;   dst = xb;   base = (size_t)cb * 2048; }
  else if (cb < 10240) { src = w13; dst = w13b; base = (size_t)(cb - 2048) * 2048; }
  else                 { src = w2;  dst = w2b;  base = (size_t)(cb - 10240) * 2048; }
  size_t i = base + (size_t)threadIdx.x * 8;
  float4 f0 = *(const float4*)(src + i);
  float4 f1 = *(const float4*)(src + i + 4);
  uint4 pk;
  pk.x = (unsigned)f2b(f0.x) | ((unsigned)f2b(f0.y) << 16);
  pk.y = (unsigned)f2b(f0.z) | ((unsigned)f2b(f0.w) << 16);
  pk.z = (unsigned)f2b(f1.x) | ((unsigned)f2b(f1.y) << 16);
  pk.w = (unsigned)f2b(f1.z) | ((unsigned)f2b(f1.w) << 16);
  *(uint4*)(dst + i) = pk;
}

// ---------------- scan: 16x8 counts -> pad_off + per-(block,expert) base; pad-fill
__global__ __launch_bounds__(256) void k_scan(
    const int* __restrict__ cnt, int* __restrict__ pad_off,
    int* __restrict__ base, int* __restrict__ perm) {
  __shared__ int s_tot[E_NUM], s_off[E_NUM + 1];
  const int tid = threadIdx.x;
  if (tid == 0) {
    int off = 0;
    for (int e = 0; e < E_NUM; ++e) {
      int tot = 0;
      for (int b = 0; b < RBLK; ++b) tot += cnt[b * E_NUM + e];
      s_tot[e] = tot;
      s_off[e] = off; pad_off[e] = off;
      int run = off;
      for (int b = 0; b < RBLK; ++b) { base[b * E_NUM + e] = run; run += cnt[b * E_NUM + e]; }
      off += (tot + 127) & ~127;
    }
    s_off[E_NUM] = off; pad_off[E_NUM] = off;
  }
  __syncthreads();
  for (int e = 0; e < E_NUM; ++e) {
    int start = s_off[e] + s_tot[e];
    int end   = s_off[e + 1];
    for (int i = start + tid; i < end; i += 256) perm[i] = -1;
  }
}

// ---------------- scatter: intra-block rank (LDS atomics only) -> perm/inv ------
__global__ __launch_bounds__(256) void k_scatter(
    const int* __restrict__ tids, const int* __restrict__ base,
    int* __restrict__ perm, int* __restrict__ inv) {
  __shared__ int l_cnt[E_NUM];
  const int b = blockIdx.x, tid = threadIdx.x;
  if (tid < E_NUM) l_cnt[tid] = 0;
  __syncthreads();
  int t = b * 256 + tid;
  int i0 = tids[t * 2], i1 = tids[t * 2 + 1];
  int r0 = atomicAdd(&l_cnt[i0], 1);
  int s0 = base[b * E_NUM + i0] + r0;
  perm[s0] = t * 2; inv[t * 2] = s0;
  int r1 = atomicAdd(&l_cnt[i1], 1);
  int s1 = base[b * E_NUM + i1] + r1;
  perm[s1] = t * 2 + 1; inv[t * 2 + 1] = s1;
}

// ---------------- GEMM1: h = gelu(x@w1^T) * (x@w3^T) ----------------
// Grid dim3(16, 72), blockIdx.x = col-block (FAST): round-robin dispatch pins
// cb -> XCD, so each (expert, cb) w13 slice stays in one XCD's L2. Do NOT
// swizzle blockIdx (round 3: FETCH 194 MB, 2x slower).
// __launch_bounds__(256, 2): LDS (64 KB) caps residency at 2 blocks/CU, so
// asking for more (round 3/4's (256,4)) only squeezes VGPRs 72->64 and loses
// K-loop latency-hiding ILP — measured 55 -> 94 us regression. Keep at 2.
// 128 padded rows x 64 unique i-cols (128 MFMA cols: 64 w1 ++ 64 w3 rows
// interleaved in 32-row segments). Wave (wm,wn) 2x2; ni 0,1 = g, ni 2,3 = u.
__global__ __launch_bounds__(256, 2) void k_gemm1(
    const unsigned short* __restrict__ xbf,
    const unsigned short* __restrict__ w13b,
    const int* __restrict__ perm, const int* __restrict__ pad_off,
    unsigned short* __restrict__ h_buf) {
  __shared__ __align__(16) unsigned short a_lds[128 * 64];
  __shared__ __align__(16) unsigned short b_lds[128 * 64];
  const int tid = threadIdx.x;
  const int wave = tid >> 6, lane = tid & 63;
  const int row0 = blockIdx.y * 128;
  if (row0 >= pad_off[E_NUM]) return;
  int e = 0;
#pragma unroll
  for (int i = 1; i < E_NUM; ++i) if (row0 >= pad_off[i]) e = i;
  const int iBase = blockIdx.x * 64;

  const int srcChunk = (lane & 7) ^ ((lane >> 3) & 7);

  const unsigned short* agbase[4];
#pragma unroll
  for (int j = 0; j < 4; ++j) {
    int r = j * 32 + wave * 8 + (lane >> 3);
    int p = perm[row0 + r];
    int tok = (p < 0) ? 0 : (p >> 1);
    agbase[j] = xbf + (size_t)tok * H_DIM + srcChunk * 8;
  }
  const unsigned short* bgbase[4];
#pragma unroll
  for (int j = 0; j < 4; ++j) {
    int brow = j * 32 + wave * 8 + (lane >> 3);
    int seg = brow >> 5, half = seg & 1;
    int col = iBase + (seg >> 1) * 32 + (brow & 31);
    bgbase[j] = w13b + ((size_t)e * 2 * I_DIM + half * I_DIM + col) * H_DIM + srcChunk * 8;
  }

  f32x4 acc[4][4];
#pragma unroll
  for (int mi = 0; mi < 4; ++mi)
#pragma unroll
    for (int ni = 0; ni < 4; ++ni) acc[mi][ni] = (f32x4)(0.f);

  const int wm = wave >> 1, wn = wave & 1;
  const int ml = lane & 15, quad = lane >> 4;

  for (int k0 = 0; k0 < H_DIM; k0 += 64) {
    __syncthreads();
#pragma unroll
    for (int j = 0; j < 4; ++j)
      async_copy16(agbase[j] + k0, a_lds + (j * 256 + wave * 64) * 8);
#pragma unroll
    for (int j = 0; j < 4; ++j)
      async_copy16(bgbase[j] + k0, b_lds + (j * 256 + wave * 64) * 8);
    __syncthreads();
#pragma unroll
    for (int ks = 0; ks < 2; ++ks) {
      const int ch = ((ks * 4 + quad) ^ (ml & 7)) * 8;
      bf16x8 af[4], bfr[4];
#pragma unroll
      for (int mi = 0; mi < 4; ++mi)
        af[mi] = *(const bf16x8*)(a_lds + (wm * 64 + mi * 16 + ml) * 64 + ch);
#pragma unroll
      for (int ni = 0; ni < 4; ++ni)
        bfr[ni] = *(const bf16x8*)(b_lds + (wn * 64 + ni * 16 + ml) * 64 + ch);
#pragma unroll
      for (int mi = 0; mi < 4; ++mi)
#pragma unroll
        for (int ni = 0; ni < 4; ++ni)
          acc[mi][ni] = __builtin_amdgcn_mfma_f32_16x16x32_bf16(af[mi], bfr[ni], acc[mi][ni], 0, 0, 0);
    }
  }
#pragma unroll
  for (int mi = 0; mi < 4; ++mi) {
#pragma unroll
    for (int nc = 0; nc < 2; ++nc) {
      f32x4 g = acc[mi][nc];
      f32x4 uu = acc[mi][nc + 2];
#pragma unroll
      for (int r = 0; r < 4; ++r) {
        int row = row0 + wm * 64 + mi * 16 + quad * 4 + r;
        int col = iBase + wn * 32 + nc * 16 + ml;
        float gg = g[r];
        float hv = 0.5f * gg * (1.f + erff(gg * 0.7071067811865475f)) * uu[r];
        h_buf[(size_t)row * I_DIM + col] = f2b(hv);
      }
    }
  }
}

// ---------------- GEMM2: y[slot] = h[slot] @ w2[e]^T (bf16 y, no atomics) --------
// Grid dim3(16, 72), col-fast (same XCD-affinity argument as gemm1).
// 128 rows x 64 cols per block; wave owns 32 rows x 64 cols. 24.6 KB LDS ->
// up to 6 blocks/CU; __launch_bounds__(256,2) leaves the allocator free.
__global__ __launch_bounds__(256, 2) void k_gemm2(
    const unsigned short* __restrict__ h_buf,
    const unsigned short* __restrict__ w2b,
    const int* __restrict__ pad_off,
    unsigned short* __restrict__ y) {
  __shared__ __align__(16) unsigned short a_lds[128 * 64];
  __shared__ __align__(16) unsigned short b_lds[64 * 64];
  const int tid = threadIdx.x;
  const int wave = tid >> 6, lane = tid & 63;
  const int row0 = blockIdx.y * 128;
  if (row0 >= pad_off[E_NUM]) return;
  int e = 0;
#pragma unroll
  for (int i = 1; i < E_NUM; ++i) if (row0 >= pad_off[i]) e = i;
  const int cBase = blockIdx.x * 64;
  const int srcChunk = (lane & 7) ^ ((lane >> 3) & 7);

  const unsigned short* agbase[4];
#pragma unroll
  for (int j = 0; j < 4; ++j) {
    int r = j * 32 + wave * 8 + (lane >> 3);
    agbase[j] = h_buf + (size_t)(row0 + r) * I_DIM + srcChunk * 8;
  }
  const unsigned short* bgbase[2];
#pragma unroll
  for (int j = 0; j < 2; ++j) {
    int brow = j * 32 + wave * 8 + (lane >> 3);
    bgbase[j] = w2b + ((size_t)e * H_DIM + cBase + brow) * I_DIM + srcChunk * 8;
  }
  f32x4 acc[2][4];
#pragma unroll
  for (int mi = 0; mi < 2; ++mi)
#pragma unroll
    for (int ni = 0; ni < 4; ++ni) acc[mi][ni] = (f32x4)(0.f);
  const int ml = lane & 15, quad = lane >> 4;

  for (int k0 = 0; k0 < I_DIM; k0 += 64) {
    __syncthreads();
#pragma unroll
    for (int j = 0; j < 4; ++j)
      async_copy16(agbase[j] + k0, a_lds + (j * 256 + wave * 64) * 8);
#pragma unroll
    for (int j = 0; j < 2; ++j)
      async_copy16(bgbase[j] + k0, b_lds + (j * 256 + wave * 64) * 8);
    __syncthreads();
#pragma unroll
    for (int ks = 0; ks < 2; ++ks) {
      const int ch = ((ks * 4 + quad) ^ (ml & 7)) * 8;
      bf16x8 af[2], bfr[4];
#pragma unroll
      for (int mi = 0; mi < 2; ++mi)
        af[mi] = *(const bf16x8*)(a_lds + (wave * 32 + mi * 16 + ml) * 64 + ch);
#pragma unroll
      for (int ni = 0; ni < 4; ++ni)
        bfr[ni] = *(const bf16x8*)(b_lds + (ni * 16 + ml) * 64 + ch);
#pragma unroll
      for (int mi = 0; mi < 2; ++mi)
#pragma unroll
        for (int ni = 0; ni < 4; ++ni)
          acc[mi][ni] = __builtin_amdgcn_mfma_f32_16x16x32_bf16(af[mi], bfr[ni], acc[mi][ni], 0, 0, 0);
    }
  }
#pragma unroll
  for (int mi = 0; mi < 2; ++mi) {
#pragma unroll
    for (int ni = 0; ni < 4; ++ni) {
#pragma unroll
      for (int r = 0; r < 4; ++r) {
        int row = row0 + wave * 32 + mi * 16 + quad * 4 + r;
        int col = cBase + ni * 16 + ml;
        y[(size_t)row * H_DIM + col] = f2b(acc[mi][ni][r]);
      }
    }
  }
}

// ---------------- combine: out[t] = cw0*y[slot0] + cw1*y[slot1] ----------------
__global__ void k_combine(const unsigned short* __restrict__ y,
                          const int* __restrict__ inv, const float* __restrict__ cw,
                          float* __restrict__ out) {
  const int t = blockIdx.x;
  const int c = threadIdx.x * 4;
  int s0 = inv[t * 2], s1 = inv[t * 2 + 1];
  float c0 = cw[t * 2], c1 = cw[t * 2 + 1];
  uint2 a = *(const uint2*)(y + (size_t)s0 * H_DIM + c);
  uint2 b = *(const uint2*)(y + (size_t)s1 * H_DIM + c);
  union { unsigned v; float f; } w;
  float4 o;
  float alo, ahi, blo, bhi;
  w.v = a.x << 16;          alo = w.f;
  w.v = a.x & 0xffff0000u;  ahi = w.f;
  w.v = b.x << 16;          blo = w.f;
  w.v = b.x & 0xffff0000u;  bhi = w.f;
  o.x = c0 * alo + c1 * blo;
  o.y = c0 * ahi + c1 * bhi;
  w.v = a.y << 16;          alo = w.f;
  w.v = a.y & 0xffff0000u;  ahi = w.f;
  w.v = b.y << 16;          blo = w.f;
  w.v = b.y & 0xffff0000u;  bhi = w.f;
  o.z = c0 * alo + c1 * blo;
  o.w = c0 * ahi + c1 * bhi;
  *(float4*)(out + (size_t)t * H_DIM + c) = o;
}

extern "C" void kernel_launch(void* const* d_in, const int* in_sizes, int n_in,
                              void* d_out, int out_size, void* d_ws, size_t ws_size,
                              hipStream_t stream) {
  const float* x      = (const float*)d_in[0];
  const float* logits = (const float*)d_in[1];
  const float* scale  = (const float*)d_in[2];
  const float* w13    = (const float*)d_in[3];
  const float* w2     = (const float*)d_in[4];
  float* out = (float*)d_out;

  char* ws = (char*)d_ws;
  int*   pad_off = (int*)(ws + 128);              // 9 ints
  int*   cnt     = (int*)(ws + 1024);             // RBLK*E ints
  int*   base    = (int*)(ws + 2048);             // RBLK*E ints
  int*   tids    = (int*)(ws + 4096);             // T*2 ints (32 KB)
  float* cw      = (float*)(ws + 65536);          // T*2 floats (32 KB)
  int*   perm    = (int*)(ws + 131072);           // PAD_CAP ints (36 KB)
  int*   inv     = (int*)(ws + 196608);           // T*2 ints (32 KB)
  unsigned short* xb    = (unsigned short*)(ws + 0x40000);    // 8 MB
  unsigned short* h_buf = (unsigned short*)(ws + 0x900000);   // 18.9 MB
  unsigned short* w13b  = (unsigned short*)(ws + 0x1C00000);  // 32 MB (dead after gemm1)
  unsigned short* ybuf  = w13b;                                // overlay: 18.9 MB
  unsigned short* w2b   = (unsigned short*)(ws + 0x3C00000);  // 16 MB (total 76 MB)

  k_prep<<<14336 + RBLK, 256, 0, stream>>>(x, logits, scale, w13, w2,
                                           xb, w13b, w2b, tids, cw, cnt);
  k_scan<<<1, 256, 0, stream>>>(cnt, pad_off, base, perm);
  k_scatter<<<RBLK, 256, 0, stream>>>(tids, base, perm, inv);
  k_gemm1<<<dim3(16, PAD_CAP / 128), 256, 0, stream>>>(xb, w13b, perm, pad_off, h_buf);
  k_gemm2<<<dim3(16, PAD_CAP / 128), 256, 0, stream>>>(h_buf, w2b, pad_off, ybuf);
  k_combine<<<T_TOK, 256, 0, stream>>>(ybuf, inv, cw, out);
}